// Round 4
// baseline (1298.962 us; speedup 1.0000x reference)
//
#include <hip/hip_runtime.h>

typedef __attribute__((ext_vector_type(8))) __bf16 bf16x8;
typedef __attribute__((ext_vector_type(4))) float f32x4;

#define DEV __device__ __forceinline__

DEV unsigned short f2bf(float f) {
  unsigned u = __float_as_uint(f);
  u = (u + 0x7fffu + ((u >> 16) & 1u)) >> 16;   // round-to-nearest-even
  return (unsigned short)u;
}
DEV float bf2f(unsigned short s) { return __uint_as_float(((unsigned)s) << 16); }
DEV float sigm(float x) { return 1.f / (1.f + expf(-x)); }

DEV uint4 pack8(f32x4 a, f32x4 b) {
  uint4 o;
  o.x = (unsigned)f2bf(a[0]) | ((unsigned)f2bf(a[1]) << 16);
  o.y = (unsigned)f2bf(a[2]) | ((unsigned)f2bf(a[3]) << 16);
  o.z = (unsigned)f2bf(b[0]) | ((unsigned)f2bf(b[1]) << 16);
  o.w = (unsigned)f2bf(b[2]) | ((unsigned)f2bf(b[3]) << 16);
  return o;
}

#define GL16(SRC, LDSB)                                                                    \
  __builtin_amdgcn_global_load_lds(                                                       \
      (const __attribute__((address_space(1))) unsigned int*)(SRC),                       \
      (__attribute__((address_space(3))) unsigned int*)(LDSB), 16, 0, 0)

// ---------------------------------------------------------------------------
// GEMM: C[M x N] = A[M x K] * B^T  (B stored [N x K] row-major bf16)
// R0-proven structure: 128x128 tile, BK=64, 4 waves, 32KB LDS, 2 barriers/step.
// XOR swizzle kb^=(row&7)<<4 as involution (pre-swizzled global src, swizzled
// ds_read, linear LDS dest — rule #21).
// XM: false -> (x=N tiles, y=M tiles); true -> (x=M tiles, y=N tiles) so the
// fast grid dim sweeps M and concurrent blocks share one B panel in L2.
// MODE: 0 = f32 out, 1 = bf16 out, 2 = fused-alpha partials.
// ---------------------------------------------------------------------------
template<int MODE, bool BIAS, bool XM>
__global__ __launch_bounds__(256)
void gemm_bt(const unsigned short* __restrict__ A, const unsigned short* __restrict__ Bm,
             const float* __restrict__ bias, void* __restrict__ Cv,
             const float* __restrict__ vw1, const float* __restrict__ qwf,
             const int* __restrict__ batchp, int M, int N, int K)
{
  __shared__ unsigned short sm[16384];          // 32 KB: As[128][64], Bs[128][64]
  unsigned short* As = sm;
  unsigned short* Bs = sm + 8192;

  const int tid  = threadIdx.x;
  const int lane = tid & 63;
  const int wv   = tid >> 6;
  const int wr   = (wv >> 1) << 6;              // wave row offset (0/64)
  const int wc   = (wv & 1) << 6;               // wave col offset (0/64)
  const int nBlk = XM ? blockIdx.y : blockIdx.x;
  const int mBlk = XM ? blockIdx.x : blockIdx.y;
  const long mTile = (long)mBlk << 7;
  const long nTile = (long)nBlk << 7;

  const f32x4 z4 = {0.f, 0.f, 0.f, 0.f};
  f32x4 acc[4][4];
  #pragma unroll
  for (int i = 0; i < 4; ++i)
    #pragma unroll
    for (int j = 0; j < 4; ++j) acc[i][j] = z4;

  const int crow = lane >> 3;                   // row within 8-row chunk
  const int ckb  = (lane & 7) << 4;             // linear kbyte of this lane's 16B

  for (int k0 = 0; k0 < K; k0 += 64) {
    #pragma unroll
    for (int i = 0; i < 4; ++i) {
      const int c   = (wv << 2) + i;            // chunk 0..15
      const int row = (c << 3) + crow;          // tile row 0..127
      const int kb  = ckb ^ ((row & 7) << 4);   // pre-swizzled source kbyte
      const unsigned short* sA = A + (mTile + row) * K + k0 + (kb >> 1);
      GL16(sA, (char*)As + (c << 10));
      int bn = (int)nTile + row; bn = bn < N ? bn : (N - 1);   // clamp OOB cols
      const unsigned short* sB = Bm + (long)bn * K + k0 + (kb >> 1);
      GL16(sB, (char*)Bs + (c << 10));
    }
    __syncthreads();
    #pragma unroll
    for (int kk = 0; kk < 64; kk += 32) {
      const int kbl = (kk + ((lane >> 4) << 3)) << 1;   // logical kbyte of fragment
      bf16x8 af[4], bfv[4];
      #pragma unroll
      for (int mi = 0; mi < 4; ++mi) {
        const int rr = wr + (mi << 4) + (lane & 15);
        af[mi] = *(const bf16x8*)((const char*)As + (rr << 7) + (kbl ^ ((rr & 7) << 4)));
      }
      #pragma unroll
      for (int ni = 0; ni < 4; ++ni) {
        const int rr = wc + (ni << 4) + (lane & 15);
        bfv[ni] = *(const bf16x8*)((const char*)Bs + (rr << 7) + (kbl ^ ((rr & 7) << 4)));
      }
      #pragma unroll
      for (int mi = 0; mi < 4; ++mi)
        #pragma unroll
        for (int ni = 0; ni < 4; ++ni)
          acc[mi][ni] = __builtin_amdgcn_mfma_f32_16x16x32_bf16(af[mi], bfv[ni], acc[mi][ni], 0, 0, 0);
    }
    __syncthreads();
  }

  if constexpr (MODE == 2) {
    // fused alpha: partial = sum_col sigm(vw1[batch[row]][col]+gemm) * qw[col]
    // one slice per (nBlk, wave-col-half); k_sg sums 4 slices + qb.
    const int slice = nBlk * 2 + (wc >> 6);
    #pragma unroll
    for (int mi = 0; mi < 4; ++mi) {
      #pragma unroll
      for (int j = 0; j < 4; ++j) {
        const long row = mTile + wr + (mi << 4) + ((lane >> 4) << 2) + j;
        const long vb = (long)batchp[row] << 8;
        float part = 0.f;
        #pragma unroll
        for (int ni = 0; ni < 4; ++ni) {
          const int col = (int)nTile + wc + (ni << 4) + (lane & 15);
          part += sigm(acc[mi][ni][j] + vw1[vb + col]) * qwf[col];
        }
        #pragma unroll
        for (int off = 1; off < 16; off <<= 1) part += __shfl_xor(part, off, 64);
        if ((lane & 15) == 0) ((float*)Cv)[(long)slice * M + row] = part;
      }
    }
  } else {
    // C/D layout col=lane&15, row=(lane>>4)*4+j (m89-verified)
    #pragma unroll
    for (int ni = 0; ni < 4; ++ni) {
      const long col = nTile + wc + (ni << 4) + (lane & 15);
      if (col < N) {
        float bv = 0.f;
        if constexpr (BIAS) bv = bias[col];
        #pragma unroll
        for (int mi = 0; mi < 4; ++mi) {
          const long row = mTile + wr + (mi << 4) + ((lane >> 4) << 2);
          #pragma unroll
          for (int j = 0; j < 4; ++j) {
            const float v = acc[mi][ni][j] + bv;
            if constexpr (MODE == 1) ((unsigned short*)Cv)[(row + j) * N + col] = f2bf(v);
            else                     ((float*)Cv)[(row + j) * N + col] = v;
          }
        }
      }
    }
  }
}

// ---------------------------------------------------------------------------
// Fused dual-GEMM + GRUCell:  h' = GRU(agg @ wih^T + bih, h @ whh^T + bhh, h)
// Block = 128 rows x 64 hidden dims -> six 128x64 gate chunks, GRU in regs.
// 8 waves (2 row-halves x 4 dim-slices), acc[4][6], BK=64.
// DOUBLE-BUFFERED 160KB dynamic LDS (2 x 80KB); occupancy is already pinned
// at 1 block/CU by VGPR (~175), so the extra LDS is free (not the m132 trap).
// stage(t+1) issues BEFORE compute(t); ONE barrier per K-step drains it.
//   buf: [0,16K) Aagg[128][64]  [16K,32K) Ah[128][64]  [32K,80K) B[6][64][64]
// Same XOR-swizzle involution as gemm_bt. hout != hin (ping-pong, no race).
// ---------------------------------------------------------------------------
__global__ __launch_bounds__(512)
void k_ggru(const unsigned short* __restrict__ agg, const unsigned short* __restrict__ hin,
            const unsigned short* __restrict__ wihb, const unsigned short* __restrict__ whhb,
            const float* __restrict__ bih, const float* __restrict__ bhh,
            unsigned short* __restrict__ hout)
{
  extern __shared__ unsigned short smd[];       // 160 KB dynamic
  const int tid  = threadIdx.x;
  const int lane = tid & 63;
  const int wv   = tid >> 6;                    // 0..7
  const int rh   = wv >> 2;                     // row half (0/1)
  const int cg   = wv & 3;                      // 16-dim slice (0..3)
  const int D0   = blockIdx.x << 6;             // hidden-dim base (0/64/128/192)
  const long mTile = (long)blockIdx.y << 7;

  const f32x4 z4 = {0.f, 0.f, 0.f, 0.f};
  f32x4 acc[4][6];
  #pragma unroll
  for (int i = 0; i < 4; ++i)
    #pragma unroll
    for (int g = 0; g < 6; ++g) acc[i][g] = z4;

  const int crow = lane >> 3;
  const int ckb  = (lane & 7) << 4;

  auto stage = [&](int buf, int k0) {
    char* base = (char*)smd + buf * 81920;
    #pragma unroll
    for (int i = 0; i < 10; ++i) {
      const int c = wv * 10 + i;                // 80 x 1KB chunks
      if (c < 32) {                             // A tiles (agg then h)
        const unsigned short* src = (c < 16) ? agg : hin;
        const int row = ((c & 15) << 3) + crow;
        const int kb  = ckb ^ ((row & 7) << 4);
        GL16(src + (mTile + row) * 256 + k0 + (kb >> 1), base + (c << 10));
      } else {                                  // B gate chunks
        const int g  = (c - 32) >> 3;           // 0..5
        const int lr = (((c - 32) & 7) << 3) + crow;   // 0..63
        const unsigned short* Ws = (g < 3) ? wihb : whhb;
        const long grow = (long)((g % 3) * 256 + D0 + lr);
        const int kb = ckb ^ ((lr & 7) << 4);
        GL16(Ws + grow * 256 + k0 + (kb >> 1), base + (c << 10));
      }
    }
  };

  stage(0, 0);
  __syncthreads();
  int cur = 0;
  for (int t = 0; t < 4; ++t) {
    if (t < 3) stage(cur ^ 1, (t + 1) << 6);    // prefetch flies under MFMA
    const char* bb = (const char*)smd + cur * 81920;
    #pragma unroll
    for (int kk = 0; kk < 64; kk += 32) {
      const int kbl = (kk + ((lane >> 4) << 3)) << 1;
      bf16x8 fa[4], fh[4], fb[6];
      #pragma unroll
      for (int mi = 0; mi < 4; ++mi) {
        const int r = (rh << 6) + (mi << 4) + (lane & 15);
        const int off = (r << 7) + (kbl ^ ((r & 7) << 4));
        fa[mi] = *(const bf16x8*)(bb + off);
        fh[mi] = *(const bf16x8*)(bb + 16384 + off);
      }
      const int lr = (cg << 4) + (lane & 15);
      const int boff = (lr << 7) + (kbl ^ ((lr & 7) << 4));
      #pragma unroll
      for (int g = 0; g < 6; ++g)
        fb[g] = *(const bf16x8*)(bb + 32768 + (g << 13) + boff);
      #pragma unroll
      for (int mi = 0; mi < 4; ++mi) {
        #pragma unroll
        for (int g = 0; g < 3; ++g)
          acc[mi][g] = __builtin_amdgcn_mfma_f32_16x16x32_bf16(fa[mi], fb[g], acc[mi][g], 0, 0, 0);
        #pragma unroll
        for (int g = 3; g < 6; ++g)
          acc[mi][g] = __builtin_amdgcn_mfma_f32_16x16x32_bf16(fh[mi], fb[g], acc[mi][g], 0, 0, 0);
      }
    }
    __syncthreads();                            // drains prefetch vmcnt + lgkm
    cur ^= 1;
  }

  // GRU combine (per-lane local) + write h'
  const int d = D0 + (cg << 4) + (lane & 15);
  const float bir = bih[d], biz = bih[256 + d], bin_ = bih[512 + d];
  const float bhr = bhh[d], bhz = bhh[256 + d], bhn  = bhh[512 + d];
  #pragma unroll
  for (int mi = 0; mi < 4; ++mi) {
    #pragma unroll
    for (int j = 0; j < 4; ++j) {
      const long row = mTile + (rh << 6) + (mi << 4) + ((lane >> 4) << 2) + j;
      const float hold = bf2f(hin[row * 256 + d]);
      const float r  = sigm(acc[mi][0][j] + bir + acc[mi][3][j] + bhr);
      const float z  = sigm(acc[mi][1][j] + biz + acc[mi][4][j] + bhz);
      const float n  = tanhf(acc[mi][2][j] + bin_ + r * (acc[mi][5][j] + bhn));
      hout[row * 256 + d] = f2bf((1.f - z) * n + z * hold);
    }
  }
}

// ---------------------------------------------------------------------------
// Elementwise / graph kernels
// ---------------------------------------------------------------------------
__global__ void k_cvt8(const float* __restrict__ in, unsigned short* __restrict__ out, long n8)
{
  const long i = (long)blockIdx.x * 256 + threadIdx.x;
  if (i >= n8) return;
  const f32x4 a = *(const f32x4*)(in + i * 8);
  const f32x4 b = *(const f32x4*)(in + i * 8 + 4);
  *(uint4*)(out + i * 8) = pack8(a, b);
}

// one dispatcher for all small weight prep (saves 6 launches):
// blocks 0..95 wih, 96..191 whh, 192..223 W1, 224..255 W2, 256..319 W3,
// 320 b12, 321..832 gated_w transpose.
__global__ void k_prep(const float* __restrict__ wih, const float* __restrict__ whh,
                       const float* __restrict__ W1, const float* __restrict__ W2,
                       const float* __restrict__ W3, const float* __restrict__ b1,
                       const float* __restrict__ b2, const float* __restrict__ gw,
                       unsigned short* __restrict__ wihb, unsigned short* __restrict__ whhb,
                       unsigned short* __restrict__ w1b, unsigned short* __restrict__ w2b,
                       unsigned short* __restrict__ w3b, float* __restrict__ b12,
                       unsigned short* __restrict__ gtw)
{
  const int b = blockIdx.x, t = threadIdx.x;
  if (b < 256) {
    const float* src; unsigned short* dst; int base;
    if (b < 96)       { src = wih; dst = wihb; base = b; }
    else if (b < 192) { src = whh; dst = whhb; base = b - 96; }
    else if (b < 224) { src = W1;  dst = w1b;  base = b - 192; }
    else              { src = W2;  dst = w2b;  base = b - 224; }
    const long i = (long)base * 256 + t;
    const f32x4 a = *(const f32x4*)(src + i * 8);
    const f32x4 c = *(const f32x4*)(src + i * 8 + 4);
    *(uint4*)(dst + i * 8) = pack8(a, c);
  } else if (b < 320) {
    const long i = (long)(b - 256) * 256 + t;
    const f32x4 a = *(const f32x4*)(W3 + i * 8);
    const f32x4 c = *(const f32x4*)(W3 + i * 8 + 4);
    *(uint4*)(w3b + i * 8) = pack8(a, c);
  } else if (b == 320) {
    b12[t] = b1[t] + b2[t];
  } else {
    const int bb = b - 321;
    const int mat = bb >> 8, n = bb & 255;
    gtw[mat * 65536 + n * 256 + t] = f2bf(gw[mat * 65536 + t * 256 + n]);
  }
}

__global__ void k_gather(const int* __restrict__ x, const float* __restrict__ emb,
                         unsigned short* __restrict__ h)
{
  const long i = (long)blockIdx.x * 256 + threadIdx.x;   // one per 8 dims
  const long node = i >> 5;
  const int  d0 = ((int)i & 31) << 3;
  const long row = (long)x[node] - 1;                    // 1-based ids
  const float* p = emb + row * 256 + d0;
  const f32x4 a = *(const f32x4*)p;
  const f32x4 b = *(const f32x4*)(p + 4);
  *(uint4*)(h + node * 256 + d0) = pack8(a, b);
}

// per-graph scatter-add: block g handles its 20 nodes / 40 edges; thread owns dim d
__global__ void k_scatter(const unsigned short* __restrict__ m, const int* __restrict__ ei,
                          unsigned short* __restrict__ agg, int E)
{
  __shared__ float aggs[20 * 256];
  __shared__ int es[40], ed[40];
  const int g = blockIdx.x;
  const int d = threadIdx.x;
  if (d < 40) es[d] = ei[g * 40 + d];
  if (d >= 128 && d < 168) ed[d - 128] = ei[E + g * 40 + (d - 128)];
  #pragma unroll
  for (int i = 0; i < 20; ++i) aggs[i * 256 + d] = 0.f;
  __syncthreads();
  for (int e = 0; e < 40; ++e) {
    const float mv = bf2f(m[(long)es[e] * 256 + d]);
    const int loc = ed[e] - g * 20;
    aggs[loc * 256 + d] += mv;     // thread-private column: no races
  }
  const long base = (long)g * (20 * 256);
  #pragma unroll
  for (int i = 0; i < 20; ++i)
    agg[base + i * 256 + d] = f2bf(aggs[i * 256 + d]);
}

// v_n gather + cat[ :256] write; last-node index via inline binsearch on batch
__global__ void k_vn(const unsigned short* __restrict__ h, const int* __restrict__ batch,
                     unsigned short* __restrict__ vn, unsigned short* __restrict__ cat, int n)
{
  const long i = (long)blockIdx.x * 256 + threadIdx.x;
  const long g = i >> 5;
  const int  d0 = ((int)i & 31) << 3;
  int lo = 0, hi = n;                     // first idx with batch[idx] > g
  while (lo < hi) { const int mid = (lo + hi) >> 1; if (batch[mid] > (int)g) hi = mid; else lo = mid + 1; }
  const uint4 v = *(const uint4*)(h + (long)(lo - 1) * 256 + d0);
  *(uint4*)(vn + g * 256 + d0) = v;
  *(uint4*)(cat + g * 512 + d0) = v;
}

__global__ void k_sg(const float* __restrict__ alph2, const float* __restrict__ qb,
                     const unsigned short* __restrict__ h, unsigned short* __restrict__ cat, int Nn)
{
  __shared__ float al[20];
  const int g = blockIdx.x, d = threadIdx.x;
  if (d < 20) {
    const int n = g * 20 + d;
    al[d] = qb[0] + alph2[n] + alph2[Nn + n] + alph2[2 * Nn + n] + alph2[3 * Nn + n];
  }
  __syncthreads();
  float s = 0.f;
  const unsigned short* hp = h + (long)g * 20 * 256 + d;
  #pragma unroll
  for (int i = 0; i < 20; ++i) s += al[i] * bf2f(hp[i * 256]);
  cat[(long)g * 512 + 256 + d] = f2bf(s);
}

// ---------------------------------------------------------------------------
extern "C" void kernel_launch(void* const* d_in, const int* in_sizes, int n_in,
                              void* d_out, int out_size, void* d_ws, size_t ws_size,
                              hipStream_t stream)
{
  const int*   x     = (const int*)  d_in[0];
  const int*   ei    = (const int*)  d_in[1];
  const int*   batch = (const int*)  d_in[2];
  const float* emb   = (const float*)d_in[3];
  const float* gw    = (const float*)d_in[4];
  const float* wih   = (const float*)d_in[5];
  const float* whh   = (const float*)d_in[6];
  const float* bih   = (const float*)d_in[7];
  const float* bhh   = (const float*)d_in[8];
  const float* W1    = (const float*)d_in[9];
  const float* b1    = (const float*)d_in[10];
  const float* W2    = (const float*)d_in[11];
  const float* b2    = (const float*)d_in[12];
  const float* qw    = (const float*)d_in[13];
  const float* qb    = (const float*)d_in[14];
  const float* W3    = (const float*)d_in[15];
  const float* b3    = (const float*)d_in[16];

  const int Nn = in_sizes[0];           // 81920 nodes
  const int E  = in_sizes[1] / 2;       // 163840 edges
  const int V  = in_sizes[3] / 256;     // 50000 vocab
  const int B  = out_size / V;          // 4096 graphs

  char* w = (char*)d_ws;
  auto take = [&](size_t bytes) { char* r = w; w += (bytes + 1023) & ~(size_t)1023; return r; };
  unsigned short* h_   = (unsigned short*)take((size_t)Nn * 256 * 2);
  unsigned short* m_   = (unsigned short*)take((size_t)Nn * 256 * 2);
  unsigned short* agg_ = (unsigned short*)take((size_t)Nn * 256 * 2);
  unsigned short* embb = (unsigned short*)take((size_t)V * 256 * 2);
  unsigned short* gtw  = (unsigned short*)take((size_t)2 * 65536 * 2);
  unsigned short* wihb = (unsigned short*)take((size_t)768 * 256 * 2);
  unsigned short* whhb = (unsigned short*)take((size_t)768 * 256 * 2);
  unsigned short* w1b  = (unsigned short*)take((size_t)65536 * 2);
  unsigned short* w2b  = (unsigned short*)take((size_t)65536 * 2);
  unsigned short* w3b  = (unsigned short*)take((size_t)131072 * 2);
  unsigned short* vnb  = (unsigned short*)take((size_t)B * 256 * 2);
  unsigned short* catb = (unsigned short*)take((size_t)B * 512 * 2);
  unsigned short* shb  = (unsigned short*)take((size_t)B * 256 * 2);
  float*          b12  = (float*)take(256 * 4);
  float*          alph2= (float*)take((size_t)4 * Nn * 4);
  float*          vw1  = (float*)take((size_t)B * 256 * 4);

  const int MBn = Nn / 128;             // 640
  const int MBb = B / 128;              // 32
  const int NBv = (V + 127) / 128;      // 391

  // allow 160KB dynamic LDS for k_ggru (host-side, capture-safe; idempotent)
  (void)hipFuncSetAttribute((const void*)k_ggru,
                            hipFuncAttributeMaxDynamicSharedMemorySize, 163840);

  // --- prep: bf16 conversions (+ gated_w transpose), fused biases ---
  k_cvt8<<<dim3(((long)V * 256 / 8 + 255) / 256), 256, 0, stream>>>(emb, embb, (long)V * 256 / 8);
  k_prep<<<dim3(833), 256, 0, stream>>>(wih, whh, W1, W2, W3, b1, b2, gw,
                                        wihb, whhb, w1b, w2b, w3b, b12, gtw);
  k_gather<<<dim3(Nn * 32 / 256), 256, 0, stream>>>(x, emb, h_);

  // --- 2x GatedGraphConv + fused GRUCell (h ping-pongs h_ <-> m_) ---
  unsigned short* hc = h_;
  unsigned short* mb = m_;
  for (int L = 0; L < 2; ++L) {
    gemm_bt<1, false, false><<<dim3(2, MBn), 256, 0, stream>>>(hc, gtw + (size_t)L * 65536, nullptr, mb,
                                                               nullptr, nullptr, nullptr, Nn, 256, 256);
    k_scatter<<<dim3(B), 256, 0, stream>>>(mb, ei, agg_, E);
    k_ggru<<<dim3(4, MBn), 512, 163840, stream>>>(agg_, hc, wihb, whhb, bih, bhh, mb);
    unsigned short* t = hc; hc = mb; mb = t;    // h' now lives in old m buffer
  }
  // after 2 swaps hc == h_ again

  // --- attention readout ---
  k_vn<<<dim3(B * 32 / 256), 256, 0, stream>>>(hc, batch, vnb, catb, Nn);
  gemm_bt<0, true, false><<<dim3(2, MBb), 256, 0, stream>>>(vnb, w1b, b12, vw1,
                                                            nullptr, nullptr, nullptr, B, 256, 256);
  // fused: alph2 slices = partial sigmoid(vw1[batch]+h@W2^T) . qw
  gemm_bt<2, false, false><<<dim3(2, MBn), 256, 0, stream>>>(hc, w2b, nullptr, alph2,
                                                             vw1, qw, batch, Nn, 256, 256);
  k_sg<<<dim3(B), 256, 0, stream>>>(alph2, qb, hc, catb, Nn);
  gemm_bt<1, true, false><<<dim3(2, MBb), 256, 0, stream>>>(catb, w3b, b3, shb,
                                                            nullptr, nullptr, nullptr, B, 256, 512);

  // --- scores = s_h @ emb^T -> d_out (f32); M-tiles on fast grid dim so
  // concurrent blocks share one embb panel in L2 ---
  gemm_bt<0, false, true><<<dim3(MBb, NBv), 256, 0, stream>>>(shb, embb, nullptr, (float*)d_out,
                                                              nullptr, nullptr, nullptr, B, V, 256);

  (void)n_in; (void)ws_size;
}

// Round 5
// 1246.191 us; speedup vs baseline: 1.0423x; 1.0423x over previous
//
#include <hip/hip_runtime.h>

typedef __attribute__((ext_vector_type(8))) __bf16 bf16x8;
typedef __attribute__((ext_vector_type(4))) float f32x4;

#define DEV __device__ __forceinline__

DEV unsigned short f2bf(float f) {
  unsigned u = __float_as_uint(f);
  u = (u + 0x7fffu + ((u >> 16) & 1u)) >> 16;   // round-to-nearest-even
  return (unsigned short)u;
}
DEV float bf2f(unsigned short s) { return __uint_as_float(((unsigned)s) << 16); }
DEV float sigm(float x) { return 1.f / (1.f + expf(-x)); }

DEV uint4 pack8(f32x4 a, f32x4 b) {
  uint4 o;
  o.x = (unsigned)f2bf(a[0]) | ((unsigned)f2bf(a[1]) << 16);
  o.y = (unsigned)f2bf(a[2]) | ((unsigned)f2bf(a[3]) << 16);
  o.z = (unsigned)f2bf(b[0]) | ((unsigned)f2bf(b[1]) << 16);
  o.w = (unsigned)f2bf(b[2]) | ((unsigned)f2bf(b[3]) << 16);
  return o;
}

#define GL16(SRC, LDSB)                                                                    \
  __builtin_amdgcn_global_load_lds(                                                       \
      (const __attribute__((address_space(1))) unsigned int*)(SRC),                       \
      (__attribute__((address_space(3))) unsigned int*)(LDSB), 16, 0, 0)

// ---------------------------------------------------------------------------
// GEMM: C[M x N] = A[M x K] * B^T  (B stored [N x K] row-major bf16)
// R0/R3-proven: 128x128 tile, BK=64, 4 waves, 32KB LDS, 2 barriers/step.
// XOR swizzle kb^=(row&7)<<4 as involution (pre-swizzled global src, swizzled
// ds_read, linear LDS dest — rule #21). Grid: x = N tiles, y = M tiles
// (XM=false proven best: concurrent blocks cover full output rows -> good
// DRAM write locality; R4's XM=true swap regressed ~+200us on scores).
// MODE: 0 = f32 out, 1 = bf16 out, 2 = fused-alpha partials.
// ---------------------------------------------------------------------------
template<int MODE, bool BIAS>
__global__ __launch_bounds__(256)
void gemm_bt(const unsigned short* __restrict__ A, const unsigned short* __restrict__ Bm,
             const float* __restrict__ bias, void* __restrict__ Cv,
             const float* __restrict__ vw1, const float* __restrict__ qwf,
             const int* __restrict__ batchp, int M, int N, int K)
{
  __shared__ unsigned short sm[16384];          // 32 KB: As[128][64], Bs[128][64]
  unsigned short* As = sm;
  unsigned short* Bs = sm + 8192;

  const int tid  = threadIdx.x;
  const int lane = tid & 63;
  const int wv   = tid >> 6;
  const int wr   = (wv >> 1) << 6;              // wave row offset (0/64)
  const int wc   = (wv & 1) << 6;               // wave col offset (0/64)
  const long mTile = (long)blockIdx.y << 7;
  const long nTile = (long)blockIdx.x << 7;

  const f32x4 z4 = {0.f, 0.f, 0.f, 0.f};
  f32x4 acc[4][4];
  #pragma unroll
  for (int i = 0; i < 4; ++i)
    #pragma unroll
    for (int j = 0; j < 4; ++j) acc[i][j] = z4;

  const int crow = lane >> 3;                   // row within 8-row chunk
  const int ckb  = (lane & 7) << 4;             // linear kbyte of this lane's 16B

  for (int k0 = 0; k0 < K; k0 += 64) {
    #pragma unroll
    for (int i = 0; i < 4; ++i) {
      const int c   = (wv << 2) + i;            // chunk 0..15
      const int row = (c << 3) + crow;          // tile row 0..127
      const int kb  = ckb ^ ((row & 7) << 4);   // pre-swizzled source kbyte
      const unsigned short* sA = A + (mTile + row) * K + k0 + (kb >> 1);
      GL16(sA, (char*)As + (c << 10));
      int bn = (int)nTile + row; bn = bn < N ? bn : (N - 1);   // clamp OOB cols
      const unsigned short* sB = Bm + (long)bn * K + k0 + (kb >> 1);
      GL16(sB, (char*)Bs + (c << 10));
    }
    __syncthreads();
    #pragma unroll
    for (int kk = 0; kk < 64; kk += 32) {
      const int kbl = (kk + ((lane >> 4) << 3)) << 1;   // logical kbyte of fragment
      bf16x8 af[4], bfv[4];
      #pragma unroll
      for (int mi = 0; mi < 4; ++mi) {
        const int rr = wr + (mi << 4) + (lane & 15);
        af[mi] = *(const bf16x8*)((const char*)As + (rr << 7) + (kbl ^ ((rr & 7) << 4)));
      }
      #pragma unroll
      for (int ni = 0; ni < 4; ++ni) {
        const int rr = wc + (ni << 4) + (lane & 15);
        bfv[ni] = *(const bf16x8*)((const char*)Bs + (rr << 7) + (kbl ^ ((rr & 7) << 4)));
      }
      #pragma unroll
      for (int mi = 0; mi < 4; ++mi)
        #pragma unroll
        for (int ni = 0; ni < 4; ++ni)
          acc[mi][ni] = __builtin_amdgcn_mfma_f32_16x16x32_bf16(af[mi], bfv[ni], acc[mi][ni], 0, 0, 0);
    }
    __syncthreads();
  }

  if constexpr (MODE == 2) {
    // fused alpha: partial = sum_col sigm(vw1[batch[row]][col]+gemm) * qw[col]
    // one slice per (nBlk, wave-col-half); k_sg sums 4 slices + qb.
    const int slice = (int)blockIdx.x * 2 + (wc >> 6);
    #pragma unroll
    for (int mi = 0; mi < 4; ++mi) {
      #pragma unroll
      for (int j = 0; j < 4; ++j) {
        const long row = mTile + wr + (mi << 4) + ((lane >> 4) << 2) + j;
        const long vb = (long)batchp[row] << 8;
        float part = 0.f;
        #pragma unroll
        for (int ni = 0; ni < 4; ++ni) {
          const int col = (int)nTile + wc + (ni << 4) + (lane & 15);
          part += sigm(acc[mi][ni][j] + vw1[vb + col]) * qwf[col];
        }
        #pragma unroll
        for (int off = 1; off < 16; off <<= 1) part += __shfl_xor(part, off, 64);
        if ((lane & 15) == 0) ((float*)Cv)[(long)slice * M + row] = part;
      }
    }
  } else {
    // C/D layout col=lane&15, row=(lane>>4)*4+j (m89-verified)
    #pragma unroll
    for (int ni = 0; ni < 4; ++ni) {
      const long col = nTile + wc + (ni << 4) + (lane & 15);
      if (col < N) {
        float bv = 0.f;
        if constexpr (BIAS) bv = bias[col];
        #pragma unroll
        for (int mi = 0; mi < 4; ++mi) {
          const long row = mTile + wr + (mi << 4) + ((lane >> 4) << 2);
          #pragma unroll
          for (int j = 0; j < 4; ++j) {
            const float v = acc[mi][ni][j] + bv;
            if constexpr (MODE == 1) ((unsigned short*)Cv)[(row + j) * N + col] = f2bf(v);
            else                     ((float*)Cv)[(row + j) * N + col] = v;
          }
        }
      }
    }
  }
}

// ---------------------------------------------------------------------------
// Fused dual-GEMM + GRUCell:  h' = GRU(agg @ wih^T + bih, h @ whh^T + bhh, h)
// Block = 128 rows x 64 hidden dims -> six 128x64 gate chunks, GRU in regs.
// 8 waves (2 row-halves x 4 dim-slices), acc[4][6], BK=64.
// DOUBLE-BUFFERED 160KB dynamic LDS (2 x 80KB). __launch_bounds__(512,2) is
// LOAD-BEARING: caps VGPR at 256 so 2 waves/SIMD hold (R4 dropped it -> VGPR
// ballooned -> 1 wave/SIMD -> ~2x slower). VGPR already pins 1 block/CU, so
// 160KB LDS costs no occupancy (not the m132 trap).
// stage(t+1) issues BEFORE compute(t); ONE barrier per K-step drains it.
//   buf: [0,16K) Aagg[128][64]  [16K,32K) Ah[128][64]  [32K,80K) B[6][64][64]
// Same XOR-swizzle involution as gemm_bt. hout != hin (ping-pong, no race).
// ---------------------------------------------------------------------------
__global__ __launch_bounds__(512, 2)
void k_ggru(const unsigned short* __restrict__ agg, const unsigned short* __restrict__ hin,
            const unsigned short* __restrict__ wihb, const unsigned short* __restrict__ whhb,
            const float* __restrict__ bih, const float* __restrict__ bhh,
            unsigned short* __restrict__ hout)
{
  extern __shared__ unsigned short smd[];       // 160 KB dynamic
  const int tid  = threadIdx.x;
  const int lane = tid & 63;
  const int wv   = tid >> 6;                    // 0..7
  const int rh   = wv >> 2;                     // row half (0/1)
  const int cg   = wv & 3;                      // 16-dim slice (0..3)
  const int D0   = blockIdx.x << 6;             // hidden-dim base (0/64/128/192)
  const long mTile = (long)blockIdx.y << 7;

  const f32x4 z4 = {0.f, 0.f, 0.f, 0.f};
  f32x4 acc[4][6];
  #pragma unroll
  for (int i = 0; i < 4; ++i)
    #pragma unroll
    for (int g = 0; g < 6; ++g) acc[i][g] = z4;

  const int crow = lane >> 3;
  const int ckb  = (lane & 7) << 4;

  auto stage = [&](int buf, int k0) {
    char* base = (char*)smd + buf * 81920;
    #pragma unroll
    for (int i = 0; i < 10; ++i) {
      const int c = wv * 10 + i;                // 80 x 1KB chunks
      if (c < 32) {                             // A tiles (agg then h)
        const unsigned short* src = (c < 16) ? agg : hin;
        const int row = ((c & 15) << 3) + crow;
        const int kb  = ckb ^ ((row & 7) << 4);
        GL16(src + (mTile + row) * 256 + k0 + (kb >> 1), base + (c << 10));
      } else {                                  // B gate chunks
        const int g  = (c - 32) >> 3;           // 0..5
        const int lr = (((c - 32) & 7) << 3) + crow;   // 0..63
        const unsigned short* Ws = (g < 3) ? wihb : whhb;
        const long grow = (long)((g % 3) * 256 + D0 + lr);
        const int kb = ckb ^ ((lr & 7) << 4);
        GL16(Ws + grow * 256 + k0 + (kb >> 1), base + (c << 10));
      }
    }
  };

  stage(0, 0);
  __syncthreads();
  int cur = 0;
  for (int t = 0; t < 4; ++t) {
    if (t < 3) stage(cur ^ 1, (t + 1) << 6);    // prefetch flies under MFMA
    const char* bb = (const char*)smd + cur * 81920;
    #pragma unroll
    for (int kk = 0; kk < 64; kk += 32) {
      const int kbl = (kk + ((lane >> 4) << 3)) << 1;
      bf16x8 fa[4], fh[4], fb[6];
      #pragma unroll
      for (int mi = 0; mi < 4; ++mi) {
        const int r = (rh << 6) + (mi << 4) + (lane & 15);
        const int off = (r << 7) + (kbl ^ ((r & 7) << 4));
        fa[mi] = *(const bf16x8*)(bb + off);
        fh[mi] = *(const bf16x8*)(bb + 16384 + off);
      }
      const int lr = (cg << 4) + (lane & 15);
      const int boff = (lr << 7) + (kbl ^ ((lr & 7) << 4));
      #pragma unroll
      for (int g = 0; g < 6; ++g)
        fb[g] = *(const bf16x8*)(bb + 32768 + (g << 13) + boff);
      #pragma unroll
      for (int mi = 0; mi < 4; ++mi) {
        #pragma unroll
        for (int g = 0; g < 3; ++g)
          acc[mi][g] = __builtin_amdgcn_mfma_f32_16x16x32_bf16(fa[mi], fb[g], acc[mi][g], 0, 0, 0);
        #pragma unroll
        for (int g = 3; g < 6; ++g)
          acc[mi][g] = __builtin_amdgcn_mfma_f32_16x16x32_bf16(fh[mi], fb[g], acc[mi][g], 0, 0, 0);
      }
    }
    __syncthreads();                            // drains prefetch vmcnt + lgkm
    cur ^= 1;
  }

  // GRU combine (per-lane local) + write h'
  const int d = D0 + (cg << 4) + (lane & 15);
  const float bir = bih[d], biz = bih[256 + d], bin_ = bih[512 + d];
  const float bhr = bhh[d], bhz = bhh[256 + d], bhn  = bhh[512 + d];
  #pragma unroll
  for (int mi = 0; mi < 4; ++mi) {
    #pragma unroll
    for (int j = 0; j < 4; ++j) {
      const long row = mTile + (rh << 6) + (mi << 4) + ((lane >> 4) << 2) + j;
      const float hold = bf2f(hin[row * 256 + d]);
      const float r  = sigm(acc[mi][0][j] + bir + acc[mi][3][j] + bhr);
      const float z  = sigm(acc[mi][1][j] + biz + acc[mi][4][j] + bhz);
      const float n  = tanhf(acc[mi][2][j] + bin_ + r * (acc[mi][5][j] + bhn));
      hout[row * 256 + d] = f2bf((1.f - z) * n + z * hold);
    }
  }
}

// ---------------------------------------------------------------------------
// Mega-prep: one launch for emb->bf16, embedding gather, all weight cvt,
// gated_w transpose, b1+b2. Block ranges:
//   [0, V8)            emb cvt       (V8 = V/8 blocks)
//   [V8, V8+Nn8)       gather        (Nn8 = Nn/8 blocks)
//   [V8+Nn8, +833)     weights: 0..95 wih, 96..191 whh, 192..223 W1,
//                      224..255 W2, 256..319 W3, 320 b12, 321..832 gw^T
// ---------------------------------------------------------------------------
__global__ void k_pre(const int* __restrict__ x, const float* __restrict__ emb,
                      unsigned short* __restrict__ embb, unsigned short* __restrict__ h,
                      const float* __restrict__ wih, const float* __restrict__ whh,
                      const float* __restrict__ W1, const float* __restrict__ W2,
                      const float* __restrict__ W3, const float* __restrict__ b1,
                      const float* __restrict__ b2, const float* __restrict__ gw,
                      unsigned short* __restrict__ wihb, unsigned short* __restrict__ whhb,
                      unsigned short* __restrict__ w1b, unsigned short* __restrict__ w2b,
                      unsigned short* __restrict__ w3b, float* __restrict__ b12,
                      unsigned short* __restrict__ gtw, int V8, int Nn8)
{
  const int b = blockIdx.x, t = threadIdx.x;
  if (b < V8) {
    const long i = (long)b * 256 + t;           // one per 8 elems of emb
    const f32x4 a = *(const f32x4*)(emb + i * 8);
    const f32x4 c = *(const f32x4*)(emb + i * 8 + 4);
    *(uint4*)(embb + i * 8) = pack8(a, c);
  } else if (b < V8 + Nn8) {
    const long i = (long)(b - V8) * 256 + t;    // one per 8 dims of h
    const long node = i >> 5;
    const int  d0 = ((int)i & 31) << 3;
    const long row = (long)x[node] - 1;         // 1-based ids
    const float* p = emb + row * 256 + d0;
    const f32x4 a = *(const f32x4*)p;
    const f32x4 c = *(const f32x4*)(p + 4);
    *(uint4*)(h + node * 256 + d0) = pack8(a, c);
  } else {
    const int bw = b - V8 - Nn8;
    if (bw < 256) {
      const float* src; unsigned short* dst; int base;
      if (bw < 96)       { src = wih; dst = wihb; base = bw; }
      else if (bw < 192) { src = whh; dst = whhb; base = bw - 96; }
      else if (bw < 224) { src = W1;  dst = w1b;  base = bw - 192; }
      else               { src = W2;  dst = w2b;  base = bw - 224; }
      const long i = (long)base * 256 + t;
      const f32x4 a = *(const f32x4*)(src + i * 8);
      const f32x4 c = *(const f32x4*)(src + i * 8 + 4);
      *(uint4*)(dst + i * 8) = pack8(a, c);
    } else if (bw < 320) {
      const long i = (long)(bw - 256) * 256 + t;
      const f32x4 a = *(const f32x4*)(W3 + i * 8);
      const f32x4 c = *(const f32x4*)(W3 + i * 8 + 4);
      *(uint4*)(w3b + i * 8) = pack8(a, c);
    } else if (bw == 320) {
      b12[t] = b1[t] + b2[t];
    } else {
      const int bb = bw - 321;
      const int mat = bb >> 8, n = bb & 255;
      gtw[mat * 65536 + n * 256 + t] = f2bf(gw[mat * 65536 + t * 256 + n]);
    }
  }
}

// per-graph scatter-add: block g handles its 20 nodes / 40 edges; thread owns dim d
__global__ void k_scatter(const unsigned short* __restrict__ m, const int* __restrict__ ei,
                          unsigned short* __restrict__ agg, int E)
{
  __shared__ float aggs[20 * 256];
  __shared__ int es[40], ed[40];
  const int g = blockIdx.x;
  const int d = threadIdx.x;
  if (d < 40) es[d] = ei[g * 40 + d];
  if (d >= 128 && d < 168) ed[d - 128] = ei[E + g * 40 + (d - 128)];
  #pragma unroll
  for (int i = 0; i < 20; ++i) aggs[i * 256 + d] = 0.f;
  __syncthreads();
  for (int e = 0; e < 40; ++e) {
    const float mv = bf2f(m[(long)es[e] * 256 + d]);
    const int loc = ed[e] - g * 20;
    aggs[loc * 256 + d] += mv;     // thread-private column: no races
  }
  const long base = (long)g * (20 * 256);
  #pragma unroll
  for (int i = 0; i < 20; ++i)
    agg[base + i * 256 + d] = f2bf(aggs[i * 256 + d]);
}

// v_n gather + cat[ :256] write; last-node index via inline binsearch on batch
__global__ void k_vn(const unsigned short* __restrict__ h, const int* __restrict__ batch,
                     unsigned short* __restrict__ vn, unsigned short* __restrict__ cat, int n)
{
  const long i = (long)blockIdx.x * 256 + threadIdx.x;
  const long g = i >> 5;
  const int  d0 = ((int)i & 31) << 3;
  int lo = 0, hi = n;                     // first idx with batch[idx] > g
  while (lo < hi) { const int mid = (lo + hi) >> 1; if (batch[mid] > (int)g) hi = mid; else lo = mid + 1; }
  const uint4 v = *(const uint4*)(h + (long)(lo - 1) * 256 + d0);
  *(uint4*)(vn + g * 256 + d0) = v;
  *(uint4*)(cat + g * 512 + d0) = v;
}

__global__ void k_sg(const float* __restrict__ alph2, const float* __restrict__ qb,
                     const unsigned short* __restrict__ h, unsigned short* __restrict__ cat, int Nn)
{
  __shared__ float al[20];
  const int g = blockIdx.x, d = threadIdx.x;
  if (d < 20) {
    const int n = g * 20 + d;
    al[d] = qb[0] + alph2[n] + alph2[Nn + n] + alph2[2 * Nn + n] + alph2[3 * Nn + n];
  }
  __syncthreads();
  float s = 0.f;
  const unsigned short* hp = h + (long)g * 20 * 256 + d;
  #pragma unroll
  for (int i = 0; i < 20; ++i) s += al[i] * bf2f(hp[i * 256]);
  cat[(long)g * 512 + 256 + d] = f2bf(s);
}

// ---------------------------------------------------------------------------
extern "C" void kernel_launch(void* const* d_in, const int* in_sizes, int n_in,
                              void* d_out, int out_size, void* d_ws, size_t ws_size,
                              hipStream_t stream)
{
  const int*   x     = (const int*)  d_in[0];
  const int*   ei    = (const int*)  d_in[1];
  const int*   batch = (const int*)  d_in[2];
  const float* emb   = (const float*)d_in[3];
  const float* gw    = (const float*)d_in[4];
  const float* wih   = (const float*)d_in[5];
  const float* whh   = (const float*)d_in[6];
  const float* bih   = (const float*)d_in[7];
  const float* bhh   = (const float*)d_in[8];
  const float* W1    = (const float*)d_in[9];
  const float* b1    = (const float*)d_in[10];
  const float* W2    = (const float*)d_in[11];
  const float* b2    = (const float*)d_in[12];
  const float* qw    = (const float*)d_in[13];
  const float* qb    = (const float*)d_in[14];
  const float* W3    = (const float*)d_in[15];
  const float* b3    = (const float*)d_in[16];

  const int Nn = in_sizes[0];           // 81920 nodes
  const int E  = in_sizes[1] / 2;       // 163840 edges
  const int V  = in_sizes[3] / 256;     // 50000 vocab
  const int B  = out_size / V;          // 4096 graphs

  char* w = (char*)d_ws;
  auto take = [&](size_t bytes) { char* r = w; w += (bytes + 1023) & ~(size_t)1023; return r; };
  unsigned short* h_   = (unsigned short*)take((size_t)Nn * 256 * 2);
  unsigned short* m_   = (unsigned short*)take((size_t)Nn * 256 * 2);
  unsigned short* agg_ = (unsigned short*)take((size_t)Nn * 256 * 2);
  unsigned short* embb = (unsigned short*)take((size_t)V * 256 * 2);
  unsigned short* gtw  = (unsigned short*)take((size_t)2 * 65536 * 2);
  unsigned short* wihb = (unsigned short*)take((size_t)768 * 256 * 2);
  unsigned short* whhb = (unsigned short*)take((size_t)768 * 256 * 2);
  unsigned short* w1b  = (unsigned short*)take((size_t)65536 * 2);
  unsigned short* w2b  = (unsigned short*)take((size_t)65536 * 2);
  unsigned short* w3b  = (unsigned short*)take((size_t)131072 * 2);
  unsigned short* vnb  = (unsigned short*)take((size_t)B * 256 * 2);
  unsigned short* catb = (unsigned short*)take((size_t)B * 512 * 2);
  unsigned short* shb  = (unsigned short*)take((size_t)B * 256 * 2);
  float*          b12  = (float*)take(256 * 4);
  float*          alph2= (float*)take((size_t)4 * Nn * 4);
  float*          vw1  = (float*)take((size_t)B * 256 * 4);

  const int MBn = Nn / 128;             // 640
  const int MBb = B / 128;              // 32
  const int NBv = (V + 127) / 128;      // 391
  const int V8  = V / 8;                // 6250
  const int Nn8 = Nn / 8;               // 10240

  // allow 160KB dynamic LDS for k_ggru (host-side, runs at capture only)
  (void)hipFuncSetAttribute((const void*)k_ggru,
                            hipFuncAttributeMaxDynamicSharedMemorySize, 163840);

  // --- prep (single launch): emb cvt + gather + weight cvt/transpose ---
  k_pre<<<dim3(V8 + Nn8 + 833), 256, 0, stream>>>(x, emb, embb, h_,
      wih, whh, W1, W2, W3, b1, b2, gw, wihb, whhb, w1b, w2b, w3b, b12, gtw, V8, Nn8);

  // --- 2x GatedGraphConv + fused GRUCell (h ping-pongs h_ <-> m_) ---
  unsigned short* hc = h_;
  unsigned short* mb = m_;
  for (int L = 0; L < 2; ++L) {
    gemm_bt<1, false><<<dim3(2, MBn), 256, 0, stream>>>(hc, gtw + (size_t)L * 65536, nullptr, mb,
                                                        nullptr, nullptr, nullptr, Nn, 256, 256);
    k_scatter<<<dim3(B), 256, 0, stream>>>(mb, ei, agg_, E);
    k_ggru<<<dim3(4, MBn), 512, 163840, stream>>>(agg_, hc, wihb, whhb, bih, bhh, mb);
    unsigned short* t = hc; hc = mb; mb = t;    // h' now lives in old m buffer
  }
  // after 2 swaps hc == h_ again

  // --- attention readout ---
  k_vn<<<dim3(B * 32 / 256), 256, 0, stream>>>(hc, batch, vnb, catb, Nn);
  gemm_bt<0, true><<<dim3(2, MBb), 256, 0, stream>>>(vnb, w1b, b12, vw1,
                                                     nullptr, nullptr, nullptr, B, 256, 256);
  // fused: alph2 slices = partial sigmoid(vw1[batch]+h@W2^T) . qw
  gemm_bt<2, false><<<dim3(2, MBn), 256, 0, stream>>>(hc, w2b, nullptr, alph2,
                                                      vw1, qw, batch, Nn, 256, 256);
  k_sg<<<dim3(B), 256, 0, stream>>>(alph2, qb, hc, catb, Nn);
  gemm_bt<1, true><<<dim3(2, MBb), 256, 0, stream>>>(catb, w3b, b3, shb,
                                                     nullptr, nullptr, nullptr, B, 256, 512);

  // --- scores = s_h @ emb^T -> d_out (f32); x = N tiles (proven layout) ---
  gemm_bt<0, false><<<dim3(NBv, MBb), 256, 0, stream>>>(shb, embb, nullptr, (float*)d_out,
                                                        nullptr, nullptr, nullptr, B, V, 256);

  (void)n_in; (void)ws_size;
}

// Round 6
// 809.363 us; speedup vs baseline: 1.6049x; 1.5397x over previous
//
#include <hip/hip_runtime.h>

typedef __attribute__((ext_vector_type(8))) __bf16 bf16x8;
typedef __attribute__((ext_vector_type(4))) float f32x4;

#define DEV __device__ __forceinline__

DEV unsigned short f2bf(float f) {
  unsigned u = __float_as_uint(f);
  u = (u + 0x7fffu + ((u >> 16) & 1u)) >> 16;   // round-to-nearest-even
  return (unsigned short)u;
}
DEV float bf2f(unsigned short s) { return __uint_as_float(((unsigned)s) << 16); }
DEV float sigm(float x) { return 1.f / (1.f + expf(-x)); }

DEV uint4 pack8(f32x4 a, f32x4 b) {
  uint4 o;
  o.x = (unsigned)f2bf(a[0]) | ((unsigned)f2bf(a[1]) << 16);
  o.y = (unsigned)f2bf(a[2]) | ((unsigned)f2bf(a[3]) << 16);
  o.z = (unsigned)f2bf(b[0]) | ((unsigned)f2bf(b[1]) << 16);
  o.w = (unsigned)f2bf(b[2]) | ((unsigned)f2bf(b[3]) << 16);
  return o;
}

#define GL16(SRC, LDSB)                                                                    \
  __builtin_amdgcn_global_load_lds(                                                       \
      (const __attribute__((address_space(1))) unsigned int*)(SRC),                       \
      (__attribute__((address_space(3))) unsigned int*)(LDSB), 16, 0, 0)

// ---------------------------------------------------------------------------
// GEMM: C[M x N] = A[M x K] * B^T  (B stored [N x K] row-major bf16)
// 831us-proven: 128x128 tile, BK=64, 4 waves, 32KB LDS, 2 barriers/step.
// XOR swizzle kb^=(row&7)<<4 as involution (pre-swizzled global src, swizzled
// ds_read, linear LDS dest — rule #21). Grid: x = N tiles, y = M tiles.
// MODE: 0 = f32 out, 1 = bf16 out, 2 = fused-alpha partials.
// ---------------------------------------------------------------------------
template<int MODE, bool BIAS>
__global__ __launch_bounds__(256)
void gemm_bt(const unsigned short* __restrict__ A, const unsigned short* __restrict__ Bm,
             const float* __restrict__ bias, void* __restrict__ Cv,
             const float* __restrict__ vw1, const float* __restrict__ qwf,
             const int* __restrict__ batchp, int M, int N, int K)
{
  __shared__ unsigned short sm[16384];          // 32 KB: As[128][64], Bs[128][64]
  unsigned short* As = sm;
  unsigned short* Bs = sm + 8192;

  const int tid  = threadIdx.x;
  const int lane = tid & 63;
  const int wv   = tid >> 6;
  const int wr   = (wv >> 1) << 6;              // wave row offset (0/64)
  const int wc   = (wv & 1) << 6;               // wave col offset (0/64)
  const long mTile = (long)blockIdx.y << 7;
  const long nTile = (long)blockIdx.x << 7;

  const f32x4 z4 = {0.f, 0.f, 0.f, 0.f};
  f32x4 acc[4][4];
  #pragma unroll
  for (int i = 0; i < 4; ++i)
    #pragma unroll
    for (int j = 0; j < 4; ++j) acc[i][j] = z4;

  const int crow = lane >> 3;                   // row within 8-row chunk
  const int ckb  = (lane & 7) << 4;             // linear kbyte of this lane's 16B

  for (int k0 = 0; k0 < K; k0 += 64) {
    #pragma unroll
    for (int i = 0; i < 4; ++i) {
      const int c   = (wv << 2) + i;            // chunk 0..15
      const int row = (c << 3) + crow;          // tile row 0..127
      const int kb  = ckb ^ ((row & 7) << 4);   // pre-swizzled source kbyte
      const unsigned short* sA = A + (mTile + row) * K + k0 + (kb >> 1);
      GL16(sA, (char*)As + (c << 10));
      int bn = (int)nTile + row; bn = bn < N ? bn : (N - 1);   // clamp OOB cols
      const unsigned short* sB = Bm + (long)bn * K + k0 + (kb >> 1);
      GL16(sB, (char*)Bs + (c << 10));
    }
    __syncthreads();
    #pragma unroll
    for (int kk = 0; kk < 64; kk += 32) {
      const int kbl = (kk + ((lane >> 4) << 3)) << 1;   // logical kbyte of fragment
      bf16x8 af[4], bfv[4];
      #pragma unroll
      for (int mi = 0; mi < 4; ++mi) {
        const int rr = wr + (mi << 4) + (lane & 15);
        af[mi] = *(const bf16x8*)((const char*)As + (rr << 7) + (kbl ^ ((rr & 7) << 4)));
      }
      #pragma unroll
      for (int ni = 0; ni < 4; ++ni) {
        const int rr = wc + (ni << 4) + (lane & 15);
        bfv[ni] = *(const bf16x8*)((const char*)Bs + (rr << 7) + (kbl ^ ((rr & 7) << 4)));
      }
      #pragma unroll
      for (int mi = 0; mi < 4; ++mi)
        #pragma unroll
        for (int ni = 0; ni < 4; ++ni)
          acc[mi][ni] = __builtin_amdgcn_mfma_f32_16x16x32_bf16(af[mi], bfv[ni], acc[mi][ni], 0, 0, 0);
    }
    __syncthreads();
  }

  if constexpr (MODE == 2) {
    // fused alpha: partial = sum_col sigm(vw1[batch[row]][col]+gemm) * qw[col]
    // one slice per (nBlk, wave-col-half); k_sg sums 4 slices + qb.
    const int slice = (int)blockIdx.x * 2 + (wc >> 6);
    #pragma unroll
    for (int mi = 0; mi < 4; ++mi) {
      #pragma unroll
      for (int j = 0; j < 4; ++j) {
        const long row = mTile + wr + (mi << 4) + ((lane >> 4) << 2) + j;
        const long vb = (long)batchp[row] << 8;
        float part = 0.f;
        #pragma unroll
        for (int ni = 0; ni < 4; ++ni) {
          const int col = (int)nTile + wc + (ni << 4) + (lane & 15);
          part += sigm(acc[mi][ni][j] + vw1[vb + col]) * qwf[col];
        }
        #pragma unroll
        for (int off = 1; off < 16; off <<= 1) part += __shfl_xor(part, off, 64);
        if ((lane & 15) == 0) ((float*)Cv)[(long)slice * M + row] = part;
      }
    }
  } else {
    // C/D layout col=lane&15, row=(lane>>4)*4+j (m89-verified)
    #pragma unroll
    for (int ni = 0; ni < 4; ++ni) {
      const long col = nTile + wc + (ni << 4) + (lane & 15);
      if (col < N) {
        float bv = 0.f;
        if constexpr (BIAS) bv = bias[col];
        #pragma unroll
        for (int mi = 0; mi < 4; ++mi) {
          const long row = mTile + wr + (mi << 4) + ((lane >> 4) << 2);
          #pragma unroll
          for (int j = 0; j < 4; ++j) {
            const float v = acc[mi][ni][j] + bv;
            if constexpr (MODE == 1) ((unsigned short*)Cv)[(row + j) * N + col] = f2bf(v);
            else                     ((float*)Cv)[(row + j) * N + col] = v;
          }
        }
      }
    }
  }
}

// ---------------------------------------------------------------------------
// Fused dual-GEMM + GRUCell:  h' = GRU(agg @ wih^T + bih, h @ whh^T + bhh, h)
// EXACT 831us-proven version: single-buffered 80KB dynamic LDS, 8 waves
// (2 row-halves x 4 dim-slices), acc[4][6], BK=64, two barriers per K-step.
// __launch_bounds__(512, 2) is LOAD-BEARING (VGPR cap -> 2 waves/SIMD).
// DO NOT double-buffer: R4/R5 proved the 160KB dbuf variant costs ~+420us
// (compiler can't disambiguate in-flight gload_lds writes from ds_reads of
// the other buffer -> full vmcnt drain before fragments / VGPR spill risk).
//   [0,16K) Aagg[128][64]  [16K,32K) Ah[128][64]  [32K,80K) B[6][64][64]
// Same XOR-swizzle involution as gemm_bt. hout != hin (ping-pong, no race).
// ---------------------------------------------------------------------------
__global__ __launch_bounds__(512, 2)
void k_ggru(const unsigned short* __restrict__ agg, const unsigned short* __restrict__ hin,
            const unsigned short* __restrict__ wihb, const unsigned short* __restrict__ whhb,
            const float* __restrict__ bih, const float* __restrict__ bhh,
            unsigned short* __restrict__ hout)
{
  extern __shared__ unsigned short sm[];        // 80 KB dynamic
  const int tid  = threadIdx.x;
  const int lane = tid & 63;
  const int wv   = tid >> 6;                    // 0..7
  const int rh   = wv >> 2;                     // row half (0/1)
  const int cg   = wv & 3;                      // 16-dim slice (0..3)
  const int D0   = blockIdx.x << 6;             // hidden-dim base (0/64/128/192)
  const long mTile = (long)blockIdx.y << 7;

  const f32x4 z4 = {0.f, 0.f, 0.f, 0.f};
  f32x4 acc[4][6];
  #pragma unroll
  for (int i = 0; i < 4; ++i)
    #pragma unroll
    for (int g = 0; g < 6; ++g) acc[i][g] = z4;

  const int crow = lane >> 3;
  const int ckb  = (lane & 7) << 4;

  for (int k0 = 0; k0 < 256; k0 += 64) {
    // stage 80 x 1KB chunks; wave wv owns chunks wv*10 .. wv*10+9
    #pragma unroll
    for (int i = 0; i < 10; ++i) {
      const int c = wv * 10 + i;
      if (c < 32) {                             // A tiles (agg then h)
        const unsigned short* src = (c < 16) ? agg : hin;
        const int row = ((c & 15) << 3) + crow;
        const int kb  = ckb ^ ((row & 7) << 4);
        GL16(src + (mTile + row) * 256 + k0 + (kb >> 1), (char*)sm + (c << 10));
      } else {                                  // B gate chunks
        const int g  = (c - 32) >> 3;           // 0..5
        const int lr = (((c - 32) & 7) << 3) + crow;   // 0..63
        const unsigned short* Ws = (g < 3) ? wihb : whhb;
        const long grow = (long)((g % 3) * 256 + D0 + lr);
        const int kb = ckb ^ ((lr & 7) << 4);
        GL16(Ws + grow * 256 + k0 + (kb >> 1), (char*)sm + (c << 10));
      }
    }
    __syncthreads();
    #pragma unroll
    for (int kk = 0; kk < 64; kk += 32) {
      const int kbl = (kk + ((lane >> 4) << 3)) << 1;
      bf16x8 fa[4], fh[4], fb[6];
      #pragma unroll
      for (int mi = 0; mi < 4; ++mi) {
        const int r = (rh << 6) + (mi << 4) + (lane & 15);
        const int off = (r << 7) + (kbl ^ ((r & 7) << 4));
        fa[mi] = *(const bf16x8*)((const char*)sm + off);
        fh[mi] = *(const bf16x8*)((const char*)sm + 16384 + off);
      }
      const int lr = (cg << 4) + (lane & 15);
      const int boff = (lr << 7) + (kbl ^ ((lr & 7) << 4));
      #pragma unroll
      for (int g = 0; g < 6; ++g)
        fb[g] = *(const bf16x8*)((const char*)sm + 32768 + (g << 13) + boff);
      #pragma unroll
      for (int mi = 0; mi < 4; ++mi) {
        #pragma unroll
        for (int g = 0; g < 3; ++g)
          acc[mi][g] = __builtin_amdgcn_mfma_f32_16x16x32_bf16(fa[mi], fb[g], acc[mi][g], 0, 0, 0);
        #pragma unroll
        for (int g = 3; g < 6; ++g)
          acc[mi][g] = __builtin_amdgcn_mfma_f32_16x16x32_bf16(fh[mi], fb[g], acc[mi][g], 0, 0, 0);
      }
    }
    __syncthreads();
  }

  // GRU combine (per-lane local) + write h'
  const int d = D0 + (cg << 4) + (lane & 15);
  const float bir = bih[d], biz = bih[256 + d], bin_ = bih[512 + d];
  const float bhr = bhh[d], bhz = bhh[256 + d], bhn  = bhh[512 + d];
  #pragma unroll
  for (int mi = 0; mi < 4; ++mi) {
    #pragma unroll
    for (int j = 0; j < 4; ++j) {
      const long row = mTile + (rh << 6) + (mi << 4) + ((lane >> 4) << 2) + j;
      const float hold = bf2f(hin[row * 256 + d]);
      const float r  = sigm(acc[mi][0][j] + bir + acc[mi][3][j] + bhr);
      const float z  = sigm(acc[mi][1][j] + biz + acc[mi][4][j] + bhz);
      const float n  = tanhf(acc[mi][2][j] + bin_ + r * (acc[mi][5][j] + bhn));
      hout[row * 256 + d] = f2bf((1.f - z) * n + z * hold);
    }
  }
}

// ---------------------------------------------------------------------------
// Mega-prep: one launch for emb->bf16, embedding gather, all weight cvt,
// gated_w transpose, b1+b2. Block ranges:
//   [0, V8)            emb cvt       (V8 = V/8 blocks)
//   [V8, V8+Nn8)       gather        (Nn8 = Nn/8 blocks)
//   [V8+Nn8, +833)     weights: 0..95 wih, 96..191 whh, 192..223 W1,
//                      224..255 W2, 256..319 W3, 320 b12, 321..832 gw^T
// ---------------------------------------------------------------------------
__global__ void k_pre(const int* __restrict__ x, const float* __restrict__ emb,
                      unsigned short* __restrict__ embb, unsigned short* __restrict__ h,
                      const float* __restrict__ wih, const float* __restrict__ whh,
                      const float* __restrict__ W1, const float* __restrict__ W2,
                      const float* __restrict__ W3, const float* __restrict__ b1,
                      const float* __restrict__ b2, const float* __restrict__ gw,
                      unsigned short* __restrict__ wihb, unsigned short* __restrict__ whhb,
                      unsigned short* __restrict__ w1b, unsigned short* __restrict__ w2b,
                      unsigned short* __restrict__ w3b, float* __restrict__ b12,
                      unsigned short* __restrict__ gtw, int V8, int Nn8)
{
  const int b = blockIdx.x, t = threadIdx.x;
  if (b < V8) {
    const long i = (long)b * 256 + t;           // one per 8 elems of emb
    const f32x4 a = *(const f32x4*)(emb + i * 8);
    const f32x4 c = *(const f32x4*)(emb + i * 8 + 4);
    *(uint4*)(embb + i * 8) = pack8(a, c);
  } else if (b < V8 + Nn8) {
    const long i = (long)(b - V8) * 256 + t;    // one per 8 dims of h
    const long node = i >> 5;
    const int  d0 = ((int)i & 31) << 3;
    const long row = (long)x[node] - 1;         // 1-based ids
    const float* p = emb + row * 256 + d0;
    const f32x4 a = *(const f32x4*)p;
    const f32x4 c = *(const f32x4*)(p + 4);
    *(uint4*)(h + node * 256 + d0) = pack8(a, c);
  } else {
    const int bw = b - V8 - Nn8;
    if (bw < 256) {
      const float* src; unsigned short* dst; int base;
      if (bw < 96)       { src = wih; dst = wihb; base = bw; }
      else if (bw < 192) { src = whh; dst = whhb; base = bw - 96; }
      else if (bw < 224) { src = W1;  dst = w1b;  base = bw - 192; }
      else               { src = W2;  dst = w2b;  base = bw - 224; }
      const long i = (long)base * 256 + t;
      const f32x4 a = *(const f32x4*)(src + i * 8);
      const f32x4 c = *(const f32x4*)(src + i * 8 + 4);
      *(uint4*)(dst + i * 8) = pack8(a, c);
    } else if (bw < 320) {
      const long i = (long)(bw - 256) * 256 + t;
      const f32x4 a = *(const f32x4*)(W3 + i * 8);
      const f32x4 c = *(const f32x4*)(W3 + i * 8 + 4);
      *(uint4*)(w3b + i * 8) = pack8(a, c);
    } else if (bw == 320) {
      b12[t] = b1[t] + b2[t];
    } else {
      const int bb = bw - 321;
      const int mat = bb >> 8, n = bb & 255;
      gtw[mat * 65536 + n * 256 + t] = f2bf(gw[mat * 65536 + t * 256 + n]);
    }
  }
}

// per-graph scatter-add: block g handles its 20 nodes / 40 edges; thread owns dim d
__global__ void k_scatter(const unsigned short* __restrict__ m, const int* __restrict__ ei,
                          unsigned short* __restrict__ agg, int E)
{
  __shared__ float aggs[20 * 256];
  __shared__ int es[40], ed[40];
  const int g = blockIdx.x;
  const int d = threadIdx.x;
  if (d < 40) es[d] = ei[g * 40 + d];
  if (d >= 128 && d < 168) ed[d - 128] = ei[E + g * 40 + (d - 128)];
  #pragma unroll
  for (int i = 0; i < 20; ++i) aggs[i * 256 + d] = 0.f;
  __syncthreads();
  for (int e = 0; e < 40; ++e) {
    const float mv = bf2f(m[(long)es[e] * 256 + d]);
    const int loc = ed[e] - g * 20;
    aggs[loc * 256 + d] += mv;     // thread-private column: no races
  }
  const long base = (long)g * (20 * 256);
  #pragma unroll
  for (int i = 0; i < 20; ++i)
    agg[base + i * 256 + d] = f2bf(aggs[i * 256 + d]);
}

// v_n gather + cat[ :256] write; last-node index via inline binsearch on batch
__global__ void k_vn(const unsigned short* __restrict__ h, const int* __restrict__ batch,
                     unsigned short* __restrict__ vn, unsigned short* __restrict__ cat, int n)
{
  const long i = (long)blockIdx.x * 256 + threadIdx.x;
  const long g = i >> 5;
  const int  d0 = ((int)i & 31) << 3;
  int lo = 0, hi = n;                     // first idx with batch[idx] > g
  while (lo < hi) { const int mid = (lo + hi) >> 1; if (batch[mid] > (int)g) hi = mid; else lo = mid + 1; }
  const uint4 v = *(const uint4*)(h + (long)(lo - 1) * 256 + d0);
  *(uint4*)(vn + g * 256 + d0) = v;
  *(uint4*)(cat + g * 512 + d0) = v;
}

__global__ void k_sg(const float* __restrict__ alph2, const float* __restrict__ qb,
                     const unsigned short* __restrict__ h, unsigned short* __restrict__ cat, int Nn)
{
  __shared__ float al[20];
  const int g = blockIdx.x, d = threadIdx.x;
  if (d < 20) {
    const int n = g * 20 + d;
    al[d] = qb[0] + alph2[n] + alph2[Nn + n] + alph2[2 * Nn + n] + alph2[3 * Nn + n];
  }
  __syncthreads();
  float s = 0.f;
  const unsigned short* hp = h + (long)g * 20 * 256 + d;
  #pragma unroll
  for (int i = 0; i < 20; ++i) s += al[i] * bf2f(hp[i * 256]);
  cat[(long)g * 512 + 256 + d] = f2bf(s);
}

// ---------------------------------------------------------------------------
extern "C" void kernel_launch(void* const* d_in, const int* in_sizes, int n_in,
                              void* d_out, int out_size, void* d_ws, size_t ws_size,
                              hipStream_t stream)
{
  const int*   x     = (const int*)  d_in[0];
  const int*   ei    = (const int*)  d_in[1];
  const int*   batch = (const int*)  d_in[2];
  const float* emb   = (const float*)d_in[3];
  const float* gw    = (const float*)d_in[4];
  const float* wih   = (const float*)d_in[5];
  const float* whh   = (const float*)d_in[6];
  const float* bih   = (const float*)d_in[7];
  const float* bhh   = (const float*)d_in[8];
  const float* W1    = (const float*)d_in[9];
  const float* b1    = (const float*)d_in[10];
  const float* W2    = (const float*)d_in[11];
  const float* b2    = (const float*)d_in[12];
  const float* qw    = (const float*)d_in[13];
  const float* qb    = (const float*)d_in[14];
  const float* W3    = (const float*)d_in[15];
  const float* b3    = (const float*)d_in[16];

  const int Nn = in_sizes[0];           // 81920 nodes
  const int E  = in_sizes[1] / 2;       // 163840 edges
  const int V  = in_sizes[3] / 256;     // 50000 vocab
  const int B  = out_size / V;          // 4096 graphs

  char* w = (char*)d_ws;
  auto take = [&](size_t bytes) { char* r = w; w += (bytes + 1023) & ~(size_t)1023; return r; };
  unsigned short* h_   = (unsigned short*)take((size_t)Nn * 256 * 2);
  unsigned short* m_   = (unsigned short*)take((size_t)Nn * 256 * 2);
  unsigned short* agg_ = (unsigned short*)take((size_t)Nn * 256 * 2);
  unsigned short* embb = (unsigned short*)take((size_t)V * 256 * 2);
  unsigned short* gtw  = (unsigned short*)take((size_t)2 * 65536 * 2);
  unsigned short* wihb = (unsigned short*)take((size_t)768 * 256 * 2);
  unsigned short* whhb = (unsigned short*)take((size_t)768 * 256 * 2);
  unsigned short* w1b  = (unsigned short*)take((size_t)65536 * 2);
  unsigned short* w2b  = (unsigned short*)take((size_t)65536 * 2);
  unsigned short* w3b  = (unsigned short*)take((size_t)131072 * 2);
  unsigned short* vnb  = (unsigned short*)take((size_t)B * 256 * 2);
  unsigned short* catb = (unsigned short*)take((size_t)B * 512 * 2);
  unsigned short* shb  = (unsigned short*)take((size_t)B * 256 * 2);
  float*          b12  = (float*)take(256 * 4);
  float*          alph2= (float*)take((size_t)4 * Nn * 4);
  float*          vw1  = (float*)take((size_t)B * 256 * 4);

  const int MBn = Nn / 128;             // 640
  const int MBb = B / 128;              // 32
  const int NBv = (V + 127) / 128;      // 391
  const int V8  = V / 8;                // 6250
  const int Nn8 = Nn / 8;               // 10240

  // --- prep (single launch): emb cvt + gather + weight cvt/transpose ---
  k_pre<<<dim3(V8 + Nn8 + 833), 256, 0, stream>>>(x, emb, embb, h_,
      wih, whh, W1, W2, W3, b1, b2, gw, wihb, whhb, w1b, w2b, w3b, b12, gtw, V8, Nn8);

  // --- 2x GatedGraphConv + fused GRUCell (h ping-pongs h_ <-> m_) ---
  unsigned short* hc = h_;
  unsigned short* mb = m_;
  for (int L = 0; L < 2; ++L) {
    gemm_bt<1, false><<<dim3(2, MBn), 256, 0, stream>>>(hc, gtw + (size_t)L * 65536, nullptr, mb,
                                                        nullptr, nullptr, nullptr, Nn, 256, 256);
    k_scatter<<<dim3(B), 256, 0, stream>>>(mb, ei, agg_, E);
    k_ggru<<<dim3(4, MBn), 512, 81920, stream>>>(agg_, hc, wihb, whhb, bih, bhh, mb);
    unsigned short* t = hc; hc = mb; mb = t;    // h' now lives in old m buffer
  }
  // after 2 swaps hc == h_ again

  // --- attention readout ---
  k_vn<<<dim3(B * 32 / 256), 256, 0, stream>>>(hc, batch, vnb, catb, Nn);
  gemm_bt<0, true><<<dim3(2, MBb), 256, 0, stream>>>(vnb, w1b, b12, vw1,
                                                     nullptr, nullptr, nullptr, B, 256, 256);
  // fused: alph2 slices = partial sigmoid(vw1[batch]+h@W2^T) . qw
  gemm_bt<2, false><<<dim3(2, MBn), 256, 0, stream>>>(hc, w2b, nullptr, alph2,
                                                      vw1, qw, batch, Nn, 256, 256);
  k_sg<<<dim3(B), 256, 0, stream>>>(alph2, qb, hc, catb, Nn);
  gemm_bt<1, true><<<dim3(2, MBb), 256, 0, stream>>>(catb, w3b, b3, shb,
                                                     nullptr, nullptr, nullptr, B, 256, 512);

  // --- scores = s_h @ emb^T -> d_out (f32); x = N tiles (proven layout) ---
  gemm_bt<0, false><<<dim3(NBv, MBb), 256, 0, stream>>>(shb, embb, nullptr, (float*)d_out,
                                                        nullptr, nullptr, nullptr, B, V, 256);

  (void)n_in; (void)ws_size;
}

// Round 7
// 761.200 us; speedup vs baseline: 1.7065x; 1.0633x over previous
//
#include <hip/hip_runtime.h>

typedef __attribute__((ext_vector_type(8))) __bf16 bf16x8;
typedef __attribute__((ext_vector_type(4))) float f32x4;

#define DEV __device__ __forceinline__

DEV unsigned short f2bf(float f) {
  unsigned u = __float_as_uint(f);
  u = (u + 0x7fffu + ((u >> 16) & 1u)) >> 16;   // round-to-nearest-even
  return (unsigned short)u;
}
DEV float bf2f(unsigned short s) { return __uint_as_float(((unsigned)s) << 16); }
DEV float sigm(float x) { return 1.f / (1.f + expf(-x)); }

DEV uint4 pack8(f32x4 a, f32x4 b) {
  uint4 o;
  o.x = (unsigned)f2bf(a[0]) | ((unsigned)f2bf(a[1]) << 16);
  o.y = (unsigned)f2bf(a[2]) | ((unsigned)f2bf(a[3]) << 16);
  o.z = (unsigned)f2bf(b[0]) | ((unsigned)f2bf(b[1]) << 16);
  o.w = (unsigned)f2bf(b[2]) | ((unsigned)f2bf(b[3]) << 16);
  return o;
}

#define GL16(SRC, LDSB)                                                                    \
  __builtin_amdgcn_global_load_lds(                                                       \
      (const __attribute__((address_space(1))) unsigned int*)(SRC),                       \
      (__attribute__((address_space(3))) unsigned int*)(LDSB), 16, 0, 0)

// ---------------------------------------------------------------------------
// GEMM: C[M x N] = A[M x K] * B^T  (B stored [N x K] row-major bf16)
// 809us-proven: 128x128 tile, BK=64, 4 waves, 32KB LDS, 2 barriers/step.
// XOR swizzle kb^=(row&7)<<4 as involution (pre-swizzled global src, swizzled
// ds_read, linear LDS dest — rule #21). Grid: x = N tiles, y = M tiles.
// MODE: 0 = f32 out, 1 = bf16 out, 2 = fused-alpha partials.
// ---------------------------------------------------------------------------
template<int MODE, bool BIAS>
__global__ __launch_bounds__(256)
void gemm_bt(const unsigned short* __restrict__ A, const unsigned short* __restrict__ Bm,
             const float* __restrict__ bias, void* __restrict__ Cv,
             const float* __restrict__ vw1, const float* __restrict__ qwf,
             const int* __restrict__ batchp, int M, int N, int K)
{
  __shared__ unsigned short sm[16384];          // 32 KB: As[128][64], Bs[128][64]
  unsigned short* As = sm;
  unsigned short* Bs = sm + 8192;

  const int tid  = threadIdx.x;
  const int lane = tid & 63;
  const int wv   = tid >> 6;
  const int wr   = (wv >> 1) << 6;              // wave row offset (0/64)
  const int wc   = (wv & 1) << 6;               // wave col offset (0/64)
  const long mTile = (long)blockIdx.y << 7;
  const long nTile = (long)blockIdx.x << 7;

  const f32x4 z4 = {0.f, 0.f, 0.f, 0.f};
  f32x4 acc[4][4];
  #pragma unroll
  for (int i = 0; i < 4; ++i)
    #pragma unroll
    for (int j = 0; j < 4; ++j) acc[i][j] = z4;

  const int crow = lane >> 3;                   // row within 8-row chunk
  const int ckb  = (lane & 7) << 4;             // linear kbyte of this lane's 16B

  for (int k0 = 0; k0 < K; k0 += 64) {
    #pragma unroll
    for (int i = 0; i < 4; ++i) {
      const int c   = (wv << 2) + i;            // chunk 0..15
      const int row = (c << 3) + crow;          // tile row 0..127
      const int kb  = ckb ^ ((row & 7) << 4);   // pre-swizzled source kbyte
      const unsigned short* sA = A + (mTile + row) * K + k0 + (kb >> 1);
      GL16(sA, (char*)As + (c << 10));
      int bn = (int)nTile + row; bn = bn < N ? bn : (N - 1);   // clamp OOB cols
      const unsigned short* sB = Bm + (long)bn * K + k0 + (kb >> 1);
      GL16(sB, (char*)Bs + (c << 10));
    }
    __syncthreads();
    #pragma unroll
    for (int kk = 0; kk < 64; kk += 32) {
      const int kbl = (kk + ((lane >> 4) << 3)) << 1;   // logical kbyte of fragment
      bf16x8 af[4], bfv[4];
      #pragma unroll
      for (int mi = 0; mi < 4; ++mi) {
        const int rr = wr + (mi << 4) + (lane & 15);
        af[mi] = *(const bf16x8*)((const char*)As + (rr << 7) + (kbl ^ ((rr & 7) << 4)));
      }
      #pragma unroll
      for (int ni = 0; ni < 4; ++ni) {
        const int rr = wc + (ni << 4) + (lane & 15);
        bfv[ni] = *(const bf16x8*)((const char*)Bs + (rr << 7) + (kbl ^ ((rr & 7) << 4)));
      }
      #pragma unroll
      for (int mi = 0; mi < 4; ++mi)
        #pragma unroll
        for (int ni = 0; ni < 4; ++ni)
          acc[mi][ni] = __builtin_amdgcn_mfma_f32_16x16x32_bf16(af[mi], bfv[ni], acc[mi][ni], 0, 0, 0);
    }
    __syncthreads();
  }

  if constexpr (MODE == 2) {
    // fused alpha: partial = sum_col sigm(vw1[batch[row]][col]+gemm) * qw[col]
    // one slice per (nBlk, wave-col-half); k_sg sums 4 slices + qb.
    const int slice = (int)blockIdx.x * 2 + (wc >> 6);
    #pragma unroll
    for (int mi = 0; mi < 4; ++mi) {
      #pragma unroll
      for (int j = 0; j < 4; ++j) {
        const long row = mTile + wr + (mi << 4) + ((lane >> 4) << 2) + j;
        const long vb = (long)batchp[row] << 8;
        float part = 0.f;
        #pragma unroll
        for (int ni = 0; ni < 4; ++ni) {
          const int col = (int)nTile + wc + (ni << 4) + (lane & 15);
          part += sigm(acc[mi][ni][j] + vw1[vb + col]) * qwf[col];
        }
        #pragma unroll
        for (int off = 1; off < 16; off <<= 1) part += __shfl_xor(part, off, 64);
        if ((lane & 15) == 0) ((float*)Cv)[(long)slice * M + row] = part;
      }
    }
  } else {
    // C/D layout col=lane&15, row=(lane>>4)*4+j (m89-verified)
    #pragma unroll
    for (int ni = 0; ni < 4; ++ni) {
      const long col = nTile + wc + (ni << 4) + (lane & 15);
      if (col < N) {
        float bv = 0.f;
        if constexpr (BIAS) bv = bias[col];
        #pragma unroll
        for (int mi = 0; mi < 4; ++mi) {
          const long row = mTile + wr + (mi << 4) + ((lane >> 4) << 2);
          #pragma unroll
          for (int j = 0; j < 4; ++j) {
            const float v = acc[mi][ni][j] + bv;
            if constexpr (MODE == 1) ((unsigned short*)Cv)[(row + j) * N + col] = f2bf(v);
            else                     ((float*)Cv)[(row + j) * N + col] = v;
          }
        }
      }
    }
  }
}

// ---------------------------------------------------------------------------
// Fused dual-GEMM + GRUCell:  h' = GRU(aggh @ Wp^T + bih, h @ whh^T + bhh, h)
// where Wp = wih @ gw^T (per-layer fused weight) and aggh = scatter-add(h) —
// the m-GEMM is eliminated by associativity: scatter(h@G)@W^T = scatter(h)@(W@G^T)^T.
// EXACT 809us-proven schedule: single-buffered 80KB dynamic LDS, 8 waves
// (2 row-halves x 4 dim-slices), acc[4][6], BK=64, two barriers per K-step.
// __launch_bounds__(512, 2) is LOAD-BEARING (VGPR cap -> 2 waves/SIMD).
// DO NOT double-buffer (R4/R5: +420us).
//   [0,16K) Aagg[128][64]  [16K,32K) Ah[128][64]  [32K,80K) B[6][64][64]
// Same XOR-swizzle involution as gemm_bt. hout != hin (ping-pong, no race).
// ---------------------------------------------------------------------------
__global__ __launch_bounds__(512, 2)
void k_ggru(const unsigned short* __restrict__ agg, const unsigned short* __restrict__ hin,
            const unsigned short* __restrict__ wpb, const unsigned short* __restrict__ whhb,
            const float* __restrict__ bih, const float* __restrict__ bhh,
            unsigned short* __restrict__ hout)
{
  extern __shared__ unsigned short sm[];        // 80 KB dynamic
  const int tid  = threadIdx.x;
  const int lane = tid & 63;
  const int wv   = tid >> 6;                    // 0..7
  const int rh   = wv >> 2;                     // row half (0/1)
  const int cg   = wv & 3;                      // 16-dim slice (0..3)
  const int D0   = blockIdx.x << 6;             // hidden-dim base (0/64/128/192)
  const long mTile = (long)blockIdx.y << 7;

  const f32x4 z4 = {0.f, 0.f, 0.f, 0.f};
  f32x4 acc[4][6];
  #pragma unroll
  for (int i = 0; i < 4; ++i)
    #pragma unroll
    for (int g = 0; g < 6; ++g) acc[i][g] = z4;

  const int crow = lane >> 3;
  const int ckb  = (lane & 7) << 4;

  for (int k0 = 0; k0 < 256; k0 += 64) {
    // stage 80 x 1KB chunks; wave wv owns chunks wv*10 .. wv*10+9
    #pragma unroll
    for (int i = 0; i < 10; ++i) {
      const int c = wv * 10 + i;
      if (c < 32) {                             // A tiles (aggh then h)
        const unsigned short* src = (c < 16) ? agg : hin;
        const int row = ((c & 15) << 3) + crow;
        const int kb  = ckb ^ ((row & 7) << 4);
        GL16(src + (mTile + row) * 256 + k0 + (kb >> 1), (char*)sm + (c << 10));
      } else {                                  // B gate chunks
        const int g  = (c - 32) >> 3;           // 0..5
        const int lr = (((c - 32) & 7) << 3) + crow;   // 0..63
        const unsigned short* Ws = (g < 3) ? wpb : whhb;
        const long grow = (long)((g % 3) * 256 + D0 + lr);
        const int kb = ckb ^ ((lr & 7) << 4);
        GL16(Ws + grow * 256 + k0 + (kb >> 1), (char*)sm + (c << 10));
      }
    }
    __syncthreads();
    #pragma unroll
    for (int kk = 0; kk < 64; kk += 32) {
      const int kbl = (kk + ((lane >> 4) << 3)) << 1;
      bf16x8 fa[4], fh[4], fb[6];
      #pragma unroll
      for (int mi = 0; mi < 4; ++mi) {
        const int r = (rh << 6) + (mi << 4) + (lane & 15);
        const int off = (r << 7) + (kbl ^ ((r & 7) << 4));
        fa[mi] = *(const bf16x8*)((const char*)sm + off);
        fh[mi] = *(const bf16x8*)((const char*)sm + 16384 + off);
      }
      const int lr = (cg << 4) + (lane & 15);
      const int boff = (lr << 7) + (kbl ^ ((lr & 7) << 4));
      #pragma unroll
      for (int g = 0; g < 6; ++g)
        fb[g] = *(const bf16x8*)((const char*)sm + 32768 + (g << 13) + boff);
      #pragma unroll
      for (int mi = 0; mi < 4; ++mi) {
        #pragma unroll
        for (int g = 0; g < 3; ++g)
          acc[mi][g] = __builtin_amdgcn_mfma_f32_16x16x32_bf16(fa[mi], fb[g], acc[mi][g], 0, 0, 0);
        #pragma unroll
        for (int g = 3; g < 6; ++g)
          acc[mi][g] = __builtin_amdgcn_mfma_f32_16x16x32_bf16(fh[mi], fb[g], acc[mi][g], 0, 0, 0);
      }
    }
    __syncthreads();
  }

  // GRU combine (per-lane local) + write h'
  const int d = D0 + (cg << 4) + (lane & 15);
  const float bir = bih[d], biz = bih[256 + d], bin_ = bih[512 + d];
  const float bhr = bhh[d], bhz = bhh[256 + d], bhn  = bhh[512 + d];
  #pragma unroll
  for (int mi = 0; mi < 4; ++mi) {
    #pragma unroll
    for (int j = 0; j < 4; ++j) {
      const long row = mTile + (rh << 6) + (mi << 4) + ((lane >> 4) << 2) + j;
      const float hold = bf2f(hin[row * 256 + d]);
      const float r  = sigm(acc[mi][0][j] + bir + acc[mi][3][j] + bhr);
      const float z  = sigm(acc[mi][1][j] + biz + acc[mi][4][j] + bhz);
      const float n  = tanhf(acc[mi][2][j] + bin_ + r * (acc[mi][5][j] + bhn));
      hout[row * 256 + d] = f2bf((1.f - z) * n + z * hold);
    }
  }
}

// ---------------------------------------------------------------------------
// Mega-prep: one launch for emb->bf16, embedding gather, all weight cvt,
// gw straight copy (no transpose needed anymore), b1+b2. Block ranges:
//   [0, V8)            emb cvt       (V8 = V/8 blocks)
//   [V8, V8+Nn8)       gather        (Nn8 = Nn/8 blocks)
//   [V8+Nn8, +385)     weights: 0..95 wih, 96..191 whh, 192..223 W1,
//                      224..255 W2, 256..319 W3, 320 b12, 321..384 gw copy
// ---------------------------------------------------------------------------
__global__ void k_pre(const int* __restrict__ x, const float* __restrict__ emb,
                      unsigned short* __restrict__ embb, unsigned short* __restrict__ h,
                      const float* __restrict__ wih, const float* __restrict__ whh,
                      const float* __restrict__ W1, const float* __restrict__ W2,
                      const float* __restrict__ W3, const float* __restrict__ b1,
                      const float* __restrict__ b2, const float* __restrict__ gw,
                      unsigned short* __restrict__ wihb, unsigned short* __restrict__ whhb,
                      unsigned short* __restrict__ w1b, unsigned short* __restrict__ w2b,
                      unsigned short* __restrict__ w3b, float* __restrict__ b12,
                      unsigned short* __restrict__ gwb, int V8, int Nn8)
{
  const int b = blockIdx.x, t = threadIdx.x;
  if (b < V8) {
    const long i = (long)b * 256 + t;           // one per 8 elems of emb
    const f32x4 a = *(const f32x4*)(emb + i * 8);
    const f32x4 c = *(const f32x4*)(emb + i * 8 + 4);
    *(uint4*)(embb + i * 8) = pack8(a, c);
  } else if (b < V8 + Nn8) {
    const long i = (long)(b - V8) * 256 + t;    // one per 8 dims of h
    const long node = i >> 5;
    const int  d0 = ((int)i & 31) << 3;
    const long row = (long)x[node] - 1;         // 1-based ids
    const float* p = emb + row * 256 + d0;
    const f32x4 a = *(const f32x4*)p;
    const f32x4 c = *(const f32x4*)(p + 4);
    *(uint4*)(h + node * 256 + d0) = pack8(a, c);
  } else {
    const int bw = b - V8 - Nn8;
    const float* src; unsigned short* dst; long base;
    if (bw < 96)       { src = wih; dst = wihb; base = bw; }
    else if (bw < 192) { src = whh; dst = whhb; base = bw - 96; }
    else if (bw < 224) { src = W1;  dst = w1b;  base = bw - 192; }
    else if (bw < 256) { src = W2;  dst = w2b;  base = bw - 224; }
    else if (bw < 320) { src = W3;  dst = w3b;  base = bw - 256; }
    else if (bw == 320) { b12[t] = b1[t] + b2[t]; return; }
    else               { src = gw;  dst = gwb;  base = bw - 321; }
    const long i = base * 256 + t;
    const f32x4 a = *(const f32x4*)(src + i * 8);
    const f32x4 c = *(const f32x4*)(src + i * 8 + 4);
    *(uint4*)(dst + i * 8) = pack8(a, c);
  }
}

// per-graph scatter-add: block g handles its 20 nodes / 40 edges; thread owns dim d
__global__ void k_scatter(const unsigned short* __restrict__ m, const int* __restrict__ ei,
                          unsigned short* __restrict__ agg, int E)
{
  __shared__ float aggs[20 * 256];
  __shared__ int es[40], ed[40];
  const int g = blockIdx.x;
  const int d = threadIdx.x;
  if (d < 40) es[d] = ei[g * 40 + d];
  if (d >= 128 && d < 168) ed[d - 128] = ei[E + g * 40 + (d - 128)];
  #pragma unroll
  for (int i = 0; i < 20; ++i) aggs[i * 256 + d] = 0.f;
  __syncthreads();
  for (int e = 0; e < 40; ++e) {
    const float mv = bf2f(m[(long)es[e] * 256 + d]);
    const int loc = ed[e] - g * 20;
    aggs[loc * 256 + d] += mv;     // thread-private column: no races
  }
  const long base = (long)g * (20 * 256);
  #pragma unroll
  for (int i = 0; i < 20; ++i)
    agg[base + i * 256 + d] = f2bf(aggs[i * 256 + d]);
}

// v_n gather + cat[ :256] write; last-node index via inline binsearch on batch
__global__ void k_vn(const unsigned short* __restrict__ h, const int* __restrict__ batch,
                     unsigned short* __restrict__ vn, unsigned short* __restrict__ cat, int n)
{
  const long i = (long)blockIdx.x * 256 + threadIdx.x;
  const long g = i >> 5;
  const int  d0 = ((int)i & 31) << 3;
  int lo = 0, hi = n;                     // first idx with batch[idx] > g
  while (lo < hi) { const int mid = (lo + hi) >> 1; if (batch[mid] > (int)g) hi = mid; else lo = mid + 1; }
  const uint4 v = *(const uint4*)(h + (long)(lo - 1) * 256 + d0);
  *(uint4*)(vn + g * 256 + d0) = v;
  *(uint4*)(cat + g * 512 + d0) = v;
}

__global__ void k_sg(const float* __restrict__ alph2, const float* __restrict__ qb,
                     const unsigned short* __restrict__ h, unsigned short* __restrict__ cat, int Nn)
{
  __shared__ float al[20];
  const int g = blockIdx.x, d = threadIdx.x;
  if (d < 20) {
    const int n = g * 20 + d;
    al[d] = qb[0] + alph2[n] + alph2[Nn + n] + alph2[2 * Nn + n] + alph2[3 * Nn + n];
  }
  __syncthreads();
  float s = 0.f;
  const unsigned short* hp = h + (long)g * 20 * 256 + d;
  #pragma unroll
  for (int i = 0; i < 20; ++i) s += al[i] * bf2f(hp[i * 256]);
  cat[(long)g * 512 + 256 + d] = f2bf(s);
}

// ---------------------------------------------------------------------------
extern "C" void kernel_launch(void* const* d_in, const int* in_sizes, int n_in,
                              void* d_out, int out_size, void* d_ws, size_t ws_size,
                              hipStream_t stream)
{
  const int*   x     = (const int*)  d_in[0];
  const int*   ei    = (const int*)  d_in[1];
  const int*   batch = (const int*)  d_in[2];
  const float* emb   = (const float*)d_in[3];
  const float* gw    = (const float*)d_in[4];
  const float* wih   = (const float*)d_in[5];
  const float* whh   = (const float*)d_in[6];
  const float* bih   = (const float*)d_in[7];
  const float* bhh   = (const float*)d_in[8];
  const float* W1    = (const float*)d_in[9];
  const float* b1    = (const float*)d_in[10];
  const float* W2    = (const float*)d_in[11];
  const float* b2    = (const float*)d_in[12];
  const float* qw    = (const float*)d_in[13];
  const float* qb    = (const float*)d_in[14];
  const float* W3    = (const float*)d_in[15];
  const float* b3    = (const float*)d_in[16];

  const int Nn = in_sizes[0];           // 81920 nodes
  const int E  = in_sizes[1] / 2;       // 163840 edges
  const int V  = in_sizes[3] / 256;     // 50000 vocab
  const int B  = out_size / V;          // 4096 graphs

  char* w = (char*)d_ws;
  auto take = [&](size_t bytes) { char* r = w; w += (bytes + 1023) & ~(size_t)1023; return r; };
  unsigned short* h_   = (unsigned short*)take((size_t)Nn * 256 * 2);
  unsigned short* m_   = (unsigned short*)take((size_t)Nn * 256 * 2);
  unsigned short* agg_ = (unsigned short*)take((size_t)Nn * 256 * 2);
  unsigned short* embb = (unsigned short*)take((size_t)V * 256 * 2);
  unsigned short* gwb  = (unsigned short*)take((size_t)2 * 65536 * 2);
  unsigned short* wihb = (unsigned short*)take((size_t)768 * 256 * 2);
  unsigned short* whhb = (unsigned short*)take((size_t)768 * 256 * 2);
  unsigned short* wp0  = (unsigned short*)take((size_t)768 * 256 * 2);
  unsigned short* wp1  = (unsigned short*)take((size_t)768 * 256 * 2);
  unsigned short* w1b  = (unsigned short*)take((size_t)65536 * 2);
  unsigned short* w2b  = (unsigned short*)take((size_t)65536 * 2);
  unsigned short* w3b  = (unsigned short*)take((size_t)131072 * 2);
  unsigned short* vnb  = (unsigned short*)take((size_t)B * 256 * 2);
  unsigned short* catb = (unsigned short*)take((size_t)B * 512 * 2);
  unsigned short* shb  = (unsigned short*)take((size_t)B * 256 * 2);
  float*          b12  = (float*)take(256 * 4);
  float*          alph2= (float*)take((size_t)4 * Nn * 4);
  float*          vw1  = (float*)take((size_t)B * 256 * 4);

  const int MBn = Nn / 128;             // 640
  const int MBb = B / 128;              // 32
  const int NBv = (V + 127) / 128;      // 391
  const int V8  = V / 8;                // 6250
  const int Nn8 = Nn / 8;               // 10240

  // --- prep (single launch): emb cvt + gather + weight cvt ---
  k_pre<<<dim3(V8 + Nn8 + 385), 256, 0, stream>>>(x, emb, embb, h_,
      wih, whh, W1, W2, W3, b1, b2, gw, wihb, whhb, w1b, w2b, w3b, b12, gwb, V8, Nn8);

  // --- fused layer weights: Wp[i] = wih @ gw[i]^T  (768x256, tiny) ---
  gemm_bt<1, false><<<dim3(2, 6), 256, 0, stream>>>(wihb, gwb, nullptr, wp0,
                                                    nullptr, nullptr, nullptr, 768, 256, 256);
  gemm_bt<1, false><<<dim3(2, 6), 256, 0, stream>>>(wihb, gwb + 65536, nullptr, wp1,
                                                    nullptr, nullptr, nullptr, 768, 256, 256);

  // --- 2x GatedGraphConv + fused GRUCell (h ping-pongs h_ <-> m_) ---
  // m-GEMM eliminated: gi = scatter(h) @ Wp^T  (associativity of linear ops)
  unsigned short* hc = h_;
  unsigned short* mb = m_;
  for (int L = 0; L < 2; ++L) {
    k_scatter<<<dim3(B), 256, 0, stream>>>(hc, ei, agg_, E);
    k_ggru<<<dim3(4, MBn), 512, 81920, stream>>>(agg_, hc, (L == 0 ? wp0 : wp1), whhb,
                                                 bih, bhh, mb);
    unsigned short* t = hc; hc = mb; mb = t;    // h' now lives in old m buffer
  }
  // after 2 swaps hc == h_ again

  // --- attention readout ---
  k_vn<<<dim3(B * 32 / 256), 256, 0, stream>>>(hc, batch, vnb, catb, Nn);
  gemm_bt<0, true><<<dim3(2, MBb), 256, 0, stream>>>(vnb, w1b, b12, vw1,
                                                     nullptr, nullptr, nullptr, B, 256, 256);
  // fused: alph2 slices = partial sigmoid(vw1[batch]+h@W2^T) . qw
  gemm_bt<2, false><<<dim3(2, MBn), 256, 0, stream>>>(hc, w2b, nullptr, alph2,
                                                      vw1, qw, batch, Nn, 256, 256);
  k_sg<<<dim3(B), 256, 0, stream>>>(alph2, qb, hc, catb, Nn);
  gemm_bt<1, true><<<dim3(2, MBb), 256, 0, stream>>>(catb, w3b, b3, shb,
                                                     nullptr, nullptr, nullptr, B, 256, 512);

  // --- scores = s_h @ emb^T -> d_out (f32); x = N tiles (proven layout) ---
  gemm_bt<0, false><<<dim3(NBv, MBb), 256, 0, stream>>>(shb, embb, nullptr, (float*)d_out,
                                                        nullptr, nullptr, nullptr, B, V, 256);

  (void)n_in; (void)ws_size;
}

// Round 8
// 738.223 us; speedup vs baseline: 1.7596x; 1.0311x over previous
//
#include <hip/hip_runtime.h>

typedef __attribute__((ext_vector_type(8))) __bf16 bf16x8;
typedef __attribute__((ext_vector_type(4))) float f32x4;

#define DEV __device__ __forceinline__

DEV unsigned short f2bf(float f) {
  unsigned u = __float_as_uint(f);
  u = (u + 0x7fffu + ((u >> 16) & 1u)) >> 16;   // round-to-nearest-even
  return (unsigned short)u;
}
DEV float bf2f(unsigned short s) { return __uint_as_float(((unsigned)s) << 16); }
DEV float sigm(float x) { return 1.f / (1.f + expf(-x)); }

DEV uint4 pack8(f32x4 a, f32x4 b) {
  uint4 o;
  o.x = (unsigned)f2bf(a[0]) | ((unsigned)f2bf(a[1]) << 16);
  o.y = (unsigned)f2bf(a[2]) | ((unsigned)f2bf(a[3]) << 16);
  o.z = (unsigned)f2bf(b[0]) | ((unsigned)f2bf(b[1]) << 16);
  o.w = (unsigned)f2bf(b[2]) | ((unsigned)f2bf(b[3]) << 16);
  return o;
}

#define GL16(SRC, LDSB)                                                                    \
  __builtin_amdgcn_global_load_lds(                                                       \
      (const __attribute__((address_space(1))) unsigned int*)(SRC),                       \
      (__attribute__((address_space(3))) unsigned int*)(LDSB), 16, 0, 0)

// ---------------------------------------------------------------------------
// GEMM: C[M x N] = A[M x K] * B^T  (B stored [N x K] row-major bf16)
// 128x128 tile, BK=64, 4 waves. NEW (R8): double-buffered 64KB LDS with
// COUNTED vmcnt + RAW s_barrier (T4): stage(t+1)'s 8 global_load_lds stay in
// flight across the barrier; vmcnt(8) waits only for tile t's loads.
// __syncthreads would drain vmcnt(0) and kill the overlap (R2/R4/R5 lesson).
// XOR swizzle kb^=(row&7)<<4 as involution (pre-swizzled global src, swizzled
// ds_read, linear LDS dest — rule #21). Grid: x = N tiles, y = M tiles.
// MODE: 0 = f32 out, 1 = bf16 out, 2 = fused-alpha partials.
// ---------------------------------------------------------------------------
template<int MODE, bool BIAS>
__global__ __launch_bounds__(256)
void gemm_bt(const unsigned short* __restrict__ A, const unsigned short* __restrict__ Bm,
             const float* __restrict__ bias, void* __restrict__ Cv,
             const float* __restrict__ vw1, const float* __restrict__ qwf,
             const int* __restrict__ batchp, int M, int N, int K)
{
  __shared__ unsigned short sm[32768];          // 64 KB: 2 x {As[128][64], Bs[128][64]}

  const int tid  = threadIdx.x;
  const int lane = tid & 63;
  const int wv   = tid >> 6;
  const int wr   = (wv >> 1) << 6;              // wave row offset (0/64)
  const int wc   = (wv & 1) << 6;               // wave col offset (0/64)
  const long mTile = (long)blockIdx.y << 7;
  const long nTile = (long)blockIdx.x << 7;

  const f32x4 z4 = {0.f, 0.f, 0.f, 0.f};
  f32x4 acc[4][4];
  #pragma unroll
  for (int i = 0; i < 4; ++i)
    #pragma unroll
    for (int j = 0; j < 4; ++j) acc[i][j] = z4;

  const int crow = lane >> 3;                   // row within 8-row chunk
  const int ckb  = (lane & 7) << 4;             // linear kbyte of this lane's 16B

  auto stage = [&](int buf, int k0) {           // exactly 8 gload_lds per thread
    char* base = (char*)sm + (buf << 15);
    #pragma unroll
    for (int i = 0; i < 4; ++i) {
      const int c   = (wv << 2) + i;            // chunk 0..15
      const int row = (c << 3) + crow;          // tile row 0..127
      const int kb  = ckb ^ ((row & 7) << 4);   // pre-swizzled source kbyte
      const unsigned short* sA = A + (mTile + row) * K + k0 + (kb >> 1);
      GL16(sA, base + (c << 10));
      int bn = (int)nTile + row; bn = bn < N ? bn : (N - 1);   // clamp OOB cols
      const unsigned short* sB = Bm + (long)bn * K + k0 + (kb >> 1);
      GL16(sB, base + 16384 + (c << 10));
    }
  };

  const int nt = K >> 6;
  stage(0, 0);
  int cur = 0;
  for (int t = 0; t < nt; ++t) {
    if (t + 1 < nt) {
      stage(cur ^ 1, (t + 1) << 6);             // prefetch: stays in flight
      asm volatile("s_waitcnt vmcnt(8)" ::: "memory");   // tile t landed
    } else {
      asm volatile("s_waitcnt vmcnt(0)" ::: "memory");
    }
    __builtin_amdgcn_s_barrier();               // raw: does NOT drain vmcnt
    asm volatile("" ::: "memory");
    const char* As = (const char*)sm + (cur << 15);
    const char* Bs = As + 16384;
    #pragma unroll
    for (int kk = 0; kk < 64; kk += 32) {
      const int kbl = (kk + ((lane >> 4) << 3)) << 1;   // logical kbyte of fragment
      bf16x8 af[4], bfv[4];
      #pragma unroll
      for (int mi = 0; mi < 4; ++mi) {
        const int rr = wr + (mi << 4) + (lane & 15);
        af[mi] = *(const bf16x8*)(As + (rr << 7) + (kbl ^ ((rr & 7) << 4)));
      }
      #pragma unroll
      for (int ni = 0; ni < 4; ++ni) {
        const int rr = wc + (ni << 4) + (lane & 15);
        bfv[ni] = *(const bf16x8*)(Bs + (rr << 7) + (kbl ^ ((rr & 7) << 4)));
      }
      #pragma unroll
      for (int mi = 0; mi < 4; ++mi)
        #pragma unroll
        for (int ni = 0; ni < 4; ++ni)
          acc[mi][ni] = __builtin_amdgcn_mfma_f32_16x16x32_bf16(af[mi], bfv[ni], acc[mi][ni], 0, 0, 0);
    }
    asm volatile("" ::: "memory");              // pin ds_reads above barrier
    __builtin_amdgcn_s_barrier();               // buf free for stage(t+2)
    cur ^= 1;
  }

  if constexpr (MODE == 2) {
    // fused alpha: partial = sum_col sigm(vw1[batch[row]][col]+gemm) * qw[col]
    // one slice per (nBlk, wave-col-half); k_sg sums 4 slices + qb.
    const int slice = (int)blockIdx.x * 2 + (wc >> 6);
    #pragma unroll
    for (int mi = 0; mi < 4; ++mi) {
      #pragma unroll
      for (int j = 0; j < 4; ++j) {
        const long row = mTile + wr + (mi << 4) + ((lane >> 4) << 2) + j;
        const long vb = (long)batchp[row] << 8;
        float part = 0.f;
        #pragma unroll
        for (int ni = 0; ni < 4; ++ni) {
          const int col = (int)nTile + wc + (ni << 4) + (lane & 15);
          part += sigm(acc[mi][ni][j] + vw1[vb + col]) * qwf[col];
        }
        #pragma unroll
        for (int off = 1; off < 16; off <<= 1) part += __shfl_xor(part, off, 64);
        if ((lane & 15) == 0) ((float*)Cv)[(long)slice * M + row] = part;
      }
    }
  } else {
    // C/D layout col=lane&15, row=(lane>>4)*4+j (m89-verified)
    #pragma unroll
    for (int ni = 0; ni < 4; ++ni) {
      const long col = nTile + wc + (ni << 4) + (lane & 15);
      if (col < N) {
        float bv = 0.f;
        if constexpr (BIAS) bv = bias[col];
        #pragma unroll
        for (int mi = 0; mi < 4; ++mi) {
          const long row = mTile + wr + (mi << 4) + ((lane >> 4) << 2);
          #pragma unroll
          for (int j = 0; j < 4; ++j) {
            const float v = acc[mi][ni][j] + bv;
            if constexpr (MODE == 1) ((unsigned short*)Cv)[(row + j) * N + col] = f2bf(v);
            else                     ((float*)Cv)[(row + j) * N + col] = v;
          }
        }
      }
    }
  }
}

// ---------------------------------------------------------------------------
// Fused dual-GEMM + GRUCell:  h' = GRU(aggh @ Wp^T + bih, h @ whh^T + bhh, h)
// where Wp = wih @ gw^T (per-layer fused weight) and aggh = scatter-add(h).
// EXACT 809us-proven schedule: single-buffered 80KB dynamic LDS, 8 waves,
// acc[4][6], BK=64, two __syncthreads per K-step. __launch_bounds__(512,2)
// is LOAD-BEARING. DO NOT naive-double-buffer (R4/R5: +420us).
//   [0,16K) Aagg[128][64]  [16K,32K) Ah[128][64]  [32K,80K) B[6][64][64]
// ---------------------------------------------------------------------------
__global__ __launch_bounds__(512, 2)
void k_ggru(const unsigned short* __restrict__ agg, const unsigned short* __restrict__ hin,
            const unsigned short* __restrict__ wpb, const unsigned short* __restrict__ whhb,
            const float* __restrict__ bih, const float* __restrict__ bhh,
            unsigned short* __restrict__ hout)
{
  extern __shared__ unsigned short sm[];        // 80 KB dynamic
  const int tid  = threadIdx.x;
  const int lane = tid & 63;
  const int wv   = tid >> 6;                    // 0..7
  const int rh   = wv >> 2;                     // row half (0/1)
  const int cg   = wv & 3;                      // 16-dim slice (0..3)
  const int D0   = blockIdx.x << 6;             // hidden-dim base (0/64/128/192)
  const long mTile = (long)blockIdx.y << 7;

  const f32x4 z4 = {0.f, 0.f, 0.f, 0.f};
  f32x4 acc[4][6];
  #pragma unroll
  for (int i = 0; i < 4; ++i)
    #pragma unroll
    for (int g = 0; g < 6; ++g) acc[i][g] = z4;

  const int crow = lane >> 3;
  const int ckb  = (lane & 7) << 4;

  for (int k0 = 0; k0 < 256; k0 += 64) {
    // stage 80 x 1KB chunks; wave wv owns chunks wv*10 .. wv*10+9
    #pragma unroll
    for (int i = 0; i < 10; ++i) {
      const int c = wv * 10 + i;
      if (c < 32) {                             // A tiles (aggh then h)
        const unsigned short* src = (c < 16) ? agg : hin;
        const int row = ((c & 15) << 3) + crow;
        const int kb  = ckb ^ ((row & 7) << 4);
        GL16(src + (mTile + row) * 256 + k0 + (kb >> 1), (char*)sm + (c << 10));
      } else {                                  // B gate chunks
        const int g  = (c - 32) >> 3;           // 0..5
        const int lr = (((c - 32) & 7) << 3) + crow;   // 0..63
        const unsigned short* Ws = (g < 3) ? wpb : whhb;
        const long grow = (long)((g % 3) * 256 + D0 + lr);
        const int kb = ckb ^ ((lr & 7) << 4);
        GL16(Ws + grow * 256 + k0 + (kb >> 1), (char*)sm + (c << 10));
      }
    }
    __syncthreads();
    #pragma unroll
    for (int kk = 0; kk < 64; kk += 32) {
      const int kbl = (kk + ((lane >> 4) << 3)) << 1;
      bf16x8 fa[4], fh[4], fb[6];
      #pragma unroll
      for (int mi = 0; mi < 4; ++mi) {
        const int r = (rh << 6) + (mi << 4) + (lane & 15);
        const int off = (r << 7) + (kbl ^ ((r & 7) << 4));
        fa[mi] = *(const bf16x8*)((const char*)sm + off);
        fh[mi] = *(const bf16x8*)((const char*)sm + 16384 + off);
      }
      const int lr = (cg << 4) + (lane & 15);
      const int boff = (lr << 7) + (kbl ^ ((lr & 7) << 4));
      #pragma unroll
      for (int g = 0; g < 6; ++g)
        fb[g] = *(const bf16x8*)((const char*)sm + 32768 + (g << 13) + boff);
      #pragma unroll
      for (int mi = 0; mi < 4; ++mi) {
        #pragma unroll
        for (int g = 0; g < 3; ++g)
          acc[mi][g] = __builtin_amdgcn_mfma_f32_16x16x32_bf16(fa[mi], fb[g], acc[mi][g], 0, 0, 0);
        #pragma unroll
        for (int g = 3; g < 6; ++g)
          acc[mi][g] = __builtin_amdgcn_mfma_f32_16x16x32_bf16(fh[mi], fb[g], acc[mi][g], 0, 0, 0);
      }
    }
    __syncthreads();
  }

  // GRU combine (per-lane local) + write h'
  const int d = D0 + (cg << 4) + (lane & 15);
  const float bir = bih[d], biz = bih[256 + d], bin_ = bih[512 + d];
  const float bhr = bhh[d], bhz = bhh[256 + d], bhn  = bhh[512 + d];
  #pragma unroll
  for (int mi = 0; mi < 4; ++mi) {
    #pragma unroll
    for (int j = 0; j < 4; ++j) {
      const long row = mTile + (rh << 6) + (mi << 4) + ((lane >> 4) << 2) + j;
      const float hold = bf2f(hin[row * 256 + d]);
      const float r  = sigm(acc[mi][0][j] + bir + acc[mi][3][j] + bhr);
      const float z  = sigm(acc[mi][1][j] + biz + acc[mi][4][j] + bhz);
      const float n  = tanhf(acc[mi][2][j] + bin_ + r * (acc[mi][5][j] + bhn));
      hout[row * 256 + d] = f2bf((1.f - z) * n + z * hold);
    }
  }
}

// ---------------------------------------------------------------------------
// Mega-prep: one launch for emb->bf16, embedding gather, all weight cvt,
// gw straight copy, b1+b2. Block ranges:
//   [0, V8) emb cvt | [V8, V8+Nn8) gather | tail: weights/b12/gw
// ---------------------------------------------------------------------------
__global__ void k_pre(const int* __restrict__ x, const float* __restrict__ emb,
                      unsigned short* __restrict__ embb, unsigned short* __restrict__ h,
                      const float* __restrict__ wih, const float* __restrict__ whh,
                      const float* __restrict__ W1, const float* __restrict__ W2,
                      const float* __restrict__ W3, const float* __restrict__ b1,
                      const float* __restrict__ b2, const float* __restrict__ gw,
                      unsigned short* __restrict__ wihb, unsigned short* __restrict__ whhb,
                      unsigned short* __restrict__ w1b, unsigned short* __restrict__ w2b,
                      unsigned short* __restrict__ w3b, float* __restrict__ b12,
                      unsigned short* __restrict__ gwb, int V8, int Nn8)
{
  const int b = blockIdx.x, t = threadIdx.x;
  if (b < V8) {
    const long i = (long)b * 256 + t;           // one per 8 elems of emb
    const f32x4 a = *(const f32x4*)(emb + i * 8);
    const f32x4 c = *(const f32x4*)(emb + i * 8 + 4);
    *(uint4*)(embb + i * 8) = pack8(a, c);
  } else if (b < V8 + Nn8) {
    const long i = (long)(b - V8) * 256 + t;    // one per 8 dims of h
    const long node = i >> 5;
    const int  d0 = ((int)i & 31) << 3;
    const long row = (long)x[node] - 1;         // 1-based ids
    const float* p = emb + row * 256 + d0;
    const f32x4 a = *(const f32x4*)p;
    const f32x4 c = *(const f32x4*)(p + 4);
    *(uint4*)(h + node * 256 + d0) = pack8(a, c);
  } else {
    const int bw = b - V8 - Nn8;
    const float* src; unsigned short* dst; long base;
    if (bw < 96)       { src = wih; dst = wihb; base = bw; }
    else if (bw < 192) { src = whh; dst = whhb; base = bw - 96; }
    else if (bw < 224) { src = W1;  dst = w1b;  base = bw - 192; }
    else if (bw < 256) { src = W2;  dst = w2b;  base = bw - 224; }
    else if (bw < 320) { src = W3;  dst = w3b;  base = bw - 256; }
    else if (bw == 320) { b12[t] = b1[t] + b2[t]; return; }
    else               { src = gw;  dst = gwb;  base = bw - 321; }
    const long i = base * 256 + t;
    const f32x4 a = *(const f32x4*)(src + i * 8);
    const f32x4 c = *(const f32x4*)(src + i * 8 + 4);
    *(uint4*)(dst + i * 8) = pack8(a, c);
  }
}

// per-graph scatter-add: block g handles its 20 nodes / 40 edges; thread owns dim d
__global__ void k_scatter(const unsigned short* __restrict__ m, const int* __restrict__ ei,
                          unsigned short* __restrict__ agg, int E)
{
  __shared__ float aggs[20 * 256];
  __shared__ int es[40], ed[40];
  const int g = blockIdx.x;
  const int d = threadIdx.x;
  if (d < 40) es[d] = ei[g * 40 + d];
  if (d >= 128 && d < 168) ed[d - 128] = ei[E + g * 40 + (d - 128)];
  #pragma unroll
  for (int i = 0; i < 20; ++i) aggs[i * 256 + d] = 0.f;
  __syncthreads();
  for (int e = 0; e < 40; ++e) {
    const float mv = bf2f(m[(long)es[e] * 256 + d]);
    const int loc = ed[e] - g * 20;
    aggs[loc * 256 + d] += mv;     // thread-private column: no races
  }
  const long base = (long)g * (20 * 256);
  #pragma unroll
  for (int i = 0; i < 20; ++i)
    agg[base + i * 256 + d] = f2bf(aggs[i * 256 + d]);
}

// v_n gather + cat[ :256] write; last-node index via inline binsearch on batch
__global__ void k_vn(const unsigned short* __restrict__ h, const int* __restrict__ batch,
                     unsigned short* __restrict__ vn, unsigned short* __restrict__ cat, int n)
{
  const long i = (long)blockIdx.x * 256 + threadIdx.x;
  const long g = i >> 5;
  const int  d0 = ((int)i & 31) << 3;
  int lo = 0, hi = n;                     // first idx with batch[idx] > g
  while (lo < hi) { const int mid = (lo + hi) >> 1; if (batch[mid] > (int)g) hi = mid; else lo = mid + 1; }
  const uint4 v = *(const uint4*)(h + (long)(lo - 1) * 256 + d0);
  *(uint4*)(vn + g * 256 + d0) = v;
  *(uint4*)(cat + g * 512 + d0) = v;
}

__global__ void k_sg(const float* __restrict__ alph2, const float* __restrict__ qb,
                     const unsigned short* __restrict__ h, unsigned short* __restrict__ cat, int Nn)
{
  __shared__ float al[20];
  const int g = blockIdx.x, d = threadIdx.x;
  if (d < 20) {
    const int n = g * 20 + d;
    al[d] = qb[0] + alph2[n] + alph2[Nn + n] + alph2[2 * Nn + n] + alph2[3 * Nn + n];
  }
  __syncthreads();
  float s = 0.f;
  const unsigned short* hp = h + (long)g * 20 * 256 + d;
  #pragma unroll
  for (int i = 0; i < 20; ++i) s += al[i] * bf2f(hp[i * 256]);
  cat[(long)g * 512 + 256 + d] = f2bf(s);
}

// ---------------------------------------------------------------------------
extern "C" void kernel_launch(void* const* d_in, const int* in_sizes, int n_in,
                              void* d_out, int out_size, void* d_ws, size_t ws_size,
                              hipStream_t stream)
{
  const int*   x     = (const int*)  d_in[0];
  const int*   ei    = (const int*)  d_in[1];
  const int*   batch = (const int*)  d_in[2];
  const float* emb   = (const float*)d_in[3];
  const float* gw    = (const float*)d_in[4];
  const float* wih   = (const float*)d_in[5];
  const float* whh   = (const float*)d_in[6];
  const float* bih   = (const float*)d_in[7];
  const float* bhh   = (const float*)d_in[8];
  const float* W1    = (const float*)d_in[9];
  const float* b1    = (const float*)d_in[10];
  const float* W2    = (const float*)d_in[11];
  const float* b2    = (const float*)d_in[12];
  const float* qw    = (const float*)d_in[13];
  const float* qb    = (const float*)d_in[14];
  const float* W3    = (const float*)d_in[15];
  const float* b3    = (const float*)d_in[16];

  const int Nn = in_sizes[0];           // 81920 nodes
  const int E  = in_sizes[1] / 2;       // 163840 edges
  const int V  = in_sizes[3] / 256;     // 50000 vocab
  const int B  = out_size / V;          // 4096 graphs

  char* w = (char*)d_ws;
  auto take = [&](size_t bytes) { char* r = w; w += (bytes + 1023) & ~(size_t)1023; return r; };
  unsigned short* h_   = (unsigned short*)take((size_t)Nn * 256 * 2);
  unsigned short* m_   = (unsigned short*)take((size_t)Nn * 256 * 2);
  unsigned short* agg_ = (unsigned short*)take((size_t)Nn * 256 * 2);
  unsigned short* embb = (unsigned short*)take((size_t)V * 256 * 2);
  unsigned short* gwb  = (unsigned short*)take((size_t)2 * 65536 * 2);
  unsigned short* wihb = (unsigned short*)take((size_t)768 * 256 * 2);
  unsigned short* whhb = (unsigned short*)take((size_t)768 * 256 * 2);
  unsigned short* wp0  = (unsigned short*)take((size_t)768 * 256 * 2);
  unsigned short* wp1  = (unsigned short*)take((size_t)768 * 256 * 2);
  unsigned short* w1b  = (unsigned short*)take((size_t)65536 * 2);
  unsigned short* w2b  = (unsigned short*)take((size_t)65536 * 2);
  unsigned short* w3b  = (unsigned short*)take((size_t)131072 * 2);
  unsigned short* vnb  = (unsigned short*)take((size_t)B * 256 * 2);
  unsigned short* catb = (unsigned short*)take((size_t)B * 512 * 2);
  unsigned short* shb  = (unsigned short*)take((size_t)B * 256 * 2);
  float*          b12  = (float*)take(256 * 4);
  float*          alph2= (float*)take((size_t)4 * Nn * 4);
  float*          vw1  = (float*)take((size_t)B * 256 * 4);

  const int MBn = Nn / 128;             // 640
  const int MBb = B / 128;              // 32
  const int NBv = (V + 127) / 128;      // 391
  const int V8  = V / 8;                // 6250
  const int Nn8 = Nn / 8;               // 10240

  // --- prep (single launch): emb cvt + gather + weight cvt ---
  k_pre<<<dim3(V8 + Nn8 + 385), 256, 0, stream>>>(x, emb, embb, h_,
      wih, whh, W1, W2, W3, b1, b2, gw, wihb, whhb, w1b, w2b, w3b, b12, gwb, V8, Nn8);

  // --- fused layer weights: Wp[i] = wih @ gw[i]^T  (768x256, tiny) ---
  gemm_bt<1, false><<<dim3(2, 6), 256, 0, stream>>>(wihb, gwb, nullptr, wp0,
                                                    nullptr, nullptr, nullptr, 768, 256, 256);
  gemm_bt<1, false><<<dim3(2, 6), 256, 0, stream>>>(wihb, gwb + 65536, nullptr, wp1,
                                                    nullptr, nullptr, nullptr, 768, 256, 256);

  // --- 2x GatedGraphConv + fused GRUCell (h ping-pongs h_ <-> m_) ---
  // m-GEMM eliminated: gi = scatter(h) @ Wp^T  (associativity of linear ops)
  unsigned short* hc = h_;
  unsigned short* mb = m_;
  for (int L = 0; L < 2; ++L) {
    k_scatter<<<dim3(B), 256, 0, stream>>>(hc, ei, agg_, E);
    k_ggru<<<dim3(4, MBn), 512, 81920, stream>>>(agg_, hc, (L == 0 ? wp0 : wp1), whhb,
                                                 bih, bhh, mb);
    unsigned short* t = hc; hc = mb; mb = t;    // h' now lives in old m buffer
  }
  // after 2 swaps hc == h_ again

  // --- attention readout ---
  k_vn<<<dim3(B * 32 / 256), 256, 0, stream>>>(hc, batch, vnb, catb, Nn);
  gemm_bt<0, true><<<dim3(2, MBb), 256, 0, stream>>>(vnb, w1b, b12, vw1,
                                                     nullptr, nullptr, nullptr, B, 256, 256);
  // fused: alph2 slices = partial sigmoid(vw1[batch]+h@W2^T) . qw
  gemm_bt<2, false><<<dim3(2, MBn), 256, 0, stream>>>(hc, w2b, nullptr, alph2,
                                                      vw1, qw, batch, Nn, 256, 256);
  k_sg<<<dim3(B), 256, 0, stream>>>(alph2, qb, hc, catb, Nn);
  gemm_bt<1, true><<<dim3(2, MBb), 256, 0, stream>>>(catb, w3b, b3, shb,
                                                     nullptr, nullptr, nullptr, B, 256, 512);

  // --- scores = s_h @ emb^T -> d_out (f32); x = N tiles (proven layout) ---
  gemm_bt<0, false><<<dim3(NBv, MBb), 256, 0, stream>>>(shb, embb, nullptr, (float*)d_out,
                                                        nullptr, nullptr, nullptr, B, V, 256);

  (void)n_in; (void)ws_size;
}

// Round 9
// 691.349 us; speedup vs baseline: 1.8789x; 1.0678x over previous
//
#include <hip/hip_runtime.h>

typedef __attribute__((ext_vector_type(8))) __bf16 bf16x8;
typedef __attribute__((ext_vector_type(4))) float f32x4;

#define DEV __device__ __forceinline__

DEV unsigned short f2bf(float f) {
  unsigned u = __float_as_uint(f);
  u = (u + 0x7fffu + ((u >> 16) & 1u)) >> 16;   // round-to-nearest-even
  return (unsigned short)u;
}
DEV float bf2f(unsigned short s) { return __uint_as_float(((unsigned)s) << 16); }
DEV float sigm(float x) { return 1.f / (1.f + expf(-x)); }

DEV uint4 pack8(f32x4 a, f32x4 b) {
  uint4 o;
  o.x = (unsigned)f2bf(a[0]) | ((unsigned)f2bf(a[1]) << 16);
  o.y = (unsigned)f2bf(a[2]) | ((unsigned)f2bf(a[3]) << 16);
  o.z = (unsigned)f2bf(b[0]) | ((unsigned)f2bf(b[1]) << 16);
  o.w = (unsigned)f2bf(b[2]) | ((unsigned)f2bf(b[3]) << 16);
  return o;
}

#define GL16(SRC, LDSB)                                                                    \
  __builtin_amdgcn_global_load_lds(                                                       \
      (const __attribute__((address_space(1))) unsigned int*)(SRC),                       \
      (__attribute__((address_space(3))) unsigned int*)(LDSB), 16, 0, 0)

// ---------------------------------------------------------------------------
// GEMM: C[M x N] = A[M x K] * B^T  (B stored [N x K] row-major bf16)
// 738us-proven (R8): 128x128 tile, BK=64, 4 waves, dbuf 64KB LDS, counted
// vmcnt(8) + raw s_barrier. XOR swizzle involution (rule #21).
// Grid: x = N tiles, y = M tiles. MODE: 0 f32 out, 1 bf16 out, 2 fused-alpha.
// ---------------------------------------------------------------------------
template<int MODE, bool BIAS>
__global__ __launch_bounds__(256)
void gemm_bt(const unsigned short* __restrict__ A, const unsigned short* __restrict__ Bm,
             const float* __restrict__ bias, void* __restrict__ Cv,
             const float* __restrict__ vw1, const float* __restrict__ qwf,
             const int* __restrict__ batchp, int M, int N, int K)
{
  __shared__ unsigned short sm[32768];          // 64 KB: 2 x {As[128][64], Bs[128][64]}

  const int tid  = threadIdx.x;
  const int lane = tid & 63;
  const int wv   = tid >> 6;
  const int wr   = (wv >> 1) << 6;              // wave row offset (0/64)
  const int wc   = (wv & 1) << 6;               // wave col offset (0/64)
  const long mTile = (long)blockIdx.y << 7;
  const long nTile = (long)blockIdx.x << 7;

  const f32x4 z4 = {0.f, 0.f, 0.f, 0.f};
  f32x4 acc[4][4];
  #pragma unroll
  for (int i = 0; i < 4; ++i)
    #pragma unroll
    for (int j = 0; j < 4; ++j) acc[i][j] = z4;

  const int crow = lane >> 3;                   // row within 8-row chunk
  const int ckb  = (lane & 7) << 4;             // linear kbyte of this lane's 16B

  auto stage = [&](int buf, int k0) {           // exactly 8 gload_lds per thread
    char* base = (char*)sm + (buf << 15);
    #pragma unroll
    for (int i = 0; i < 4; ++i) {
      const int c   = (wv << 2) + i;            // chunk 0..15
      const int row = (c << 3) + crow;          // tile row 0..127
      const int kb  = ckb ^ ((row & 7) << 4);   // pre-swizzled source kbyte
      const unsigned short* sA = A + (mTile + row) * K + k0 + (kb >> 1);
      GL16(sA, base + (c << 10));
      int bn = (int)nTile + row; bn = bn < N ? bn : (N - 1);   // clamp OOB cols
      const unsigned short* sB = Bm + (long)bn * K + k0 + (kb >> 1);
      GL16(sB, base + 16384 + (c << 10));
    }
  };

  const int nt = K >> 6;
  stage(0, 0);
  int cur = 0;
  for (int t = 0; t < nt; ++t) {
    if (t + 1 < nt) {
      stage(cur ^ 1, (t + 1) << 6);             // prefetch: stays in flight
      asm volatile("s_waitcnt vmcnt(8)" ::: "memory");   // tile t landed
    } else {
      asm volatile("s_waitcnt vmcnt(0)" ::: "memory");
    }
    __builtin_amdgcn_s_barrier();               // raw: does NOT drain vmcnt
    asm volatile("" ::: "memory");
    const char* As = (const char*)sm + (cur << 15);
    const char* Bs = As + 16384;
    #pragma unroll
    for (int kk = 0; kk < 64; kk += 32) {
      const int kbl = (kk + ((lane >> 4) << 3)) << 1;   // logical kbyte of fragment
      bf16x8 af[4], bfv[4];
      #pragma unroll
      for (int mi = 0; mi < 4; ++mi) {
        const int rr = wr + (mi << 4) + (lane & 15);
        af[mi] = *(const bf16x8*)(As + (rr << 7) + (kbl ^ ((rr & 7) << 4)));
      }
      #pragma unroll
      for (int ni = 0; ni < 4; ++ni) {
        const int rr = wc + (ni << 4) + (lane & 15);
        bfv[ni] = *(const bf16x8*)(Bs + (rr << 7) + (kbl ^ ((rr & 7) << 4)));
      }
      #pragma unroll
      for (int mi = 0; mi < 4; ++mi)
        #pragma unroll
        for (int ni = 0; ni < 4; ++ni)
          acc[mi][ni] = __builtin_amdgcn_mfma_f32_16x16x32_bf16(af[mi], bfv[ni], acc[mi][ni], 0, 0, 0);
    }
    asm volatile("" ::: "memory");              // pin ds_reads above barrier
    __builtin_amdgcn_s_barrier();               // buf free for stage(t+2)
    cur ^= 1;
  }

  if constexpr (MODE == 2) {
    // fused alpha: partial = sum_col sigm(vw1[batch[row]][col]+gemm) * qw[col]
    const int slice = (int)blockIdx.x * 2 + (wc >> 6);
    #pragma unroll
    for (int mi = 0; mi < 4; ++mi) {
      #pragma unroll
      for (int j = 0; j < 4; ++j) {
        const long row = mTile + wr + (mi << 4) + ((lane >> 4) << 2) + j;
        const long vb = (long)batchp[row] << 8;
        float part = 0.f;
        #pragma unroll
        for (int ni = 0; ni < 4; ++ni) {
          const int col = (int)nTile + wc + (ni << 4) + (lane & 15);
          part += sigm(acc[mi][ni][j] + vw1[vb + col]) * qwf[col];
        }
        #pragma unroll
        for (int off = 1; off < 16; off <<= 1) part += __shfl_xor(part, off, 64);
        if ((lane & 15) == 0) ((float*)Cv)[(long)slice * M + row] = part;
      }
    }
  } else {
    // C/D layout col=lane&15, row=(lane>>4)*4+j (m89-verified)
    #pragma unroll
    for (int ni = 0; ni < 4; ++ni) {
      const long col = nTile + wc + (ni << 4) + (lane & 15);
      if (col < N) {
        float bv = 0.f;
        if constexpr (BIAS) bv = bias[col];
        #pragma unroll
        for (int mi = 0; mi < 4; ++mi) {
          const long row = mTile + wr + (mi << 4) + ((lane >> 4) << 2);
          #pragma unroll
          for (int j = 0; j < 4; ++j) {
            const float v = acc[mi][ni][j] + bv;
            if constexpr (MODE == 1) ((unsigned short*)Cv)[(row + j) * N + col] = f2bf(v);
            else                     ((float*)Cv)[(row + j) * N + col] = v;
          }
        }
      }
    }
  }
}

// ---------------------------------------------------------------------------
// 256x256-tile GEMM for the scores matmul (R9): same counted-vmcnt schedule
// as gemm_bt but 8 waves (2x4), per-wave 128x64 output, acc[8][4] (128 VGPR,
// within the (512,2) 256-cap). Halves staged bytes per FLOP vs 128^2
// (3136 blocks x 256KB = 800MB vs 12512 x 128KB = 1.6GB) — the R8 post-mortem
// showed stage-bandwidth, not barrier drain, binds this GEMM.
// 128KB dynamic LDS dbuf; 1 block/CU = 2 waves/SIMD (same occupancy as 2x
// 4-wave blocks). f32 out, no bias, col-guarded (N arbitrary).
// ---------------------------------------------------------------------------
__global__ __launch_bounds__(512, 2)
void gemm256(const unsigned short* __restrict__ A, const unsigned short* __restrict__ Bm,
             float* __restrict__ C, int M, int N, int K)
{
  extern __shared__ unsigned short smd[];       // 128 KB: 2 x {As[256][64], Bs[256][64]}
  const int tid  = threadIdx.x;
  const int lane = tid & 63;
  const int wv   = tid >> 6;                    // 0..7
  const int wr   = (wv >> 2) << 7;              // wave row offset (0/128)
  const int wc   = (wv & 3) << 6;               // wave col offset (0/64/128/192)
  const long mTile = (long)blockIdx.y << 8;
  const long nTile = (long)blockIdx.x << 8;

  const f32x4 z4 = {0.f, 0.f, 0.f, 0.f};
  f32x4 acc[8][4];
  #pragma unroll
  for (int i = 0; i < 8; ++i)
    #pragma unroll
    for (int j = 0; j < 4; ++j) acc[i][j] = z4;

  const int crow = lane >> 3;                   // row within 8-row chunk
  const int ckb  = (lane & 7) << 4;

  auto stage = [&](int buf, int k0) {           // exactly 8 gload_lds per thread
    char* base = (char*)smd + (buf << 16);
    #pragma unroll
    for (int i = 0; i < 4; ++i) {
      const int c   = (wv << 2) + i;            // chunk 0..31
      const int row = (c << 3) + crow;          // tile row 0..255
      const int kb  = ckb ^ ((row & 7) << 4);
      const unsigned short* sA = A + (mTile + row) * K + k0 + (kb >> 1);
      GL16(sA, base + (c << 10));
      int bn = (int)nTile + row; bn = bn < N ? bn : (N - 1);
      const unsigned short* sB = Bm + (long)bn * K + k0 + (kb >> 1);
      GL16(sB, base + 32768 + (c << 10));
    }
  };

  const int nt = K >> 6;
  stage(0, 0);
  int cur = 0;
  for (int t = 0; t < nt; ++t) {
    if (t + 1 < nt) {
      stage(cur ^ 1, (t + 1) << 6);
      asm volatile("s_waitcnt vmcnt(8)" ::: "memory");
    } else {
      asm volatile("s_waitcnt vmcnt(0)" ::: "memory");
    }
    __builtin_amdgcn_s_barrier();
    asm volatile("" ::: "memory");
    const char* As = (const char*)smd + (cur << 16);
    const char* Bs = As + 32768;
    #pragma unroll
    for (int kk = 0; kk < 64; kk += 32) {
      const int kbl = (kk + ((lane >> 4) << 3)) << 1;
      bf16x8 af[8], bfv[4];
      #pragma unroll
      for (int mi = 0; mi < 8; ++mi) {
        const int rr = wr + (mi << 4) + (lane & 15);
        af[mi] = *(const bf16x8*)(As + (rr << 7) + (kbl ^ ((rr & 7) << 4)));
      }
      #pragma unroll
      for (int ni = 0; ni < 4; ++ni) {
        const int rr = wc + (ni << 4) + (lane & 15);
        bfv[ni] = *(const bf16x8*)(Bs + (rr << 7) + (kbl ^ ((rr & 7) << 4)));
      }
      #pragma unroll
      for (int mi = 0; mi < 8; ++mi)
        #pragma unroll
        for (int ni = 0; ni < 4; ++ni)
          acc[mi][ni] = __builtin_amdgcn_mfma_f32_16x16x32_bf16(af[mi], bfv[ni], acc[mi][ni], 0, 0, 0);
    }
    asm volatile("" ::: "memory");
    __builtin_amdgcn_s_barrier();
    cur ^= 1;
  }

  #pragma unroll
  for (int ni = 0; ni < 4; ++ni) {
    const long col = nTile + wc + (ni << 4) + (lane & 15);
    if (col < N) {
      #pragma unroll
      for (int mi = 0; mi < 8; ++mi) {
        const long row = mTile + wr + (mi << 4) + ((lane >> 4) << 2);
        #pragma unroll
        for (int j = 0; j < 4; ++j)
          C[(row + j) * N + col] = acc[mi][ni][j];
      }
    }
  }
}

// ---------------------------------------------------------------------------
// Fused dual-GEMM + GRUCell:  h' = GRU(aggh @ Wp^T + bih, h @ whh^T + bhh, h)
// where Wp = wih @ gw^T (per-layer fused weight) and aggh = scatter-add(h).
// EXACT 809us-proven schedule: single-buffered 80KB dynamic LDS, 8 waves,
// acc[4][6], BK=64, two __syncthreads per K-step. __launch_bounds__(512,2)
// is LOAD-BEARING. DO NOT naive-double-buffer (R4/R5: +420us).
//   [0,16K) Aagg[128][64]  [16K,32K) Ah[128][64]  [32K,80K) B[6][64][64]
// ---------------------------------------------------------------------------
__global__ __launch_bounds__(512, 2)
void k_ggru(const unsigned short* __restrict__ agg, const unsigned short* __restrict__ hin,
            const unsigned short* __restrict__ wpb, const unsigned short* __restrict__ whhb,
            const float* __restrict__ bih, const float* __restrict__ bhh,
            unsigned short* __restrict__ hout)
{
  extern __shared__ unsigned short sm[];        // 80 KB dynamic
  const int tid  = threadIdx.x;
  const int lane = tid & 63;
  const int wv   = tid >> 6;                    // 0..7
  const int rh   = wv >> 2;                     // row half (0/1)
  const int cg   = wv & 3;                      // 16-dim slice (0..3)
  const int D0   = blockIdx.x << 6;             // hidden-dim base (0/64/128/192)
  const long mTile = (long)blockIdx.y << 7;

  const f32x4 z4 = {0.f, 0.f, 0.f, 0.f};
  f32x4 acc[4][6];
  #pragma unroll
  for (int i = 0; i < 4; ++i)
    #pragma unroll
    for (int g = 0; g < 6; ++g) acc[i][g] = z4;

  const int crow = lane >> 3;
  const int ckb  = (lane & 7) << 4;

  for (int k0 = 0; k0 < 256; k0 += 64) {
    // stage 80 x 1KB chunks; wave wv owns chunks wv*10 .. wv*10+9
    #pragma unroll
    for (int i = 0; i < 10; ++i) {
      const int c = wv * 10 + i;
      if (c < 32) {                             // A tiles (aggh then h)
        const unsigned short* src = (c < 16) ? agg : hin;
        const int row = ((c & 15) << 3) + crow;
        const int kb  = ckb ^ ((row & 7) << 4);
        GL16(src + (mTile + row) * 256 + k0 + (kb >> 1), (char*)sm + (c << 10));
      } else {                                  // B gate chunks
        const int g  = (c - 32) >> 3;           // 0..5
        const int lr = (((c - 32) & 7) << 3) + crow;   // 0..63
        const unsigned short* Ws = (g < 3) ? wpb : whhb;
        const long grow = (long)((g % 3) * 256 + D0 + lr);
        const int kb = ckb ^ ((lr & 7) << 4);
        GL16(Ws + grow * 256 + k0 + (kb >> 1), (char*)sm + (c << 10));
      }
    }
    __syncthreads();
    #pragma unroll
    for (int kk = 0; kk < 64; kk += 32) {
      const int kbl = (kk + ((lane >> 4) << 3)) << 1;
      bf16x8 fa[4], fh[4], fb[6];
      #pragma unroll
      for (int mi = 0; mi < 4; ++mi) {
        const int r = (rh << 6) + (mi << 4) + (lane & 15);
        const int off = (r << 7) + (kbl ^ ((r & 7) << 4));
        fa[mi] = *(const bf16x8*)((const char*)sm + off);
        fh[mi] = *(const bf16x8*)((const char*)sm + 16384 + off);
      }
      const int lr = (cg << 4) + (lane & 15);
      const int boff = (lr << 7) + (kbl ^ ((lr & 7) << 4));
      #pragma unroll
      for (int g = 0; g < 6; ++g)
        fb[g] = *(const bf16x8*)((const char*)sm + 32768 + (g << 13) + boff);
      #pragma unroll
      for (int mi = 0; mi < 4; ++mi) {
        #pragma unroll
        for (int g = 0; g < 3; ++g)
          acc[mi][g] = __builtin_amdgcn_mfma_f32_16x16x32_bf16(fa[mi], fb[g], acc[mi][g], 0, 0, 0);
        #pragma unroll
        for (int g = 3; g < 6; ++g)
          acc[mi][g] = __builtin_amdgcn_mfma_f32_16x16x32_bf16(fh[mi], fb[g], acc[mi][g], 0, 0, 0);
      }
    }
    __syncthreads();
  }

  // GRU combine (per-lane local) + write h'
  const int d = D0 + (cg << 4) + (lane & 15);
  const float bir = bih[d], biz = bih[256 + d], bin_ = bih[512 + d];
  const float bhr = bhh[d], bhz = bhh[256 + d], bhn  = bhh[512 + d];
  #pragma unroll
  for (int mi = 0; mi < 4; ++mi) {
    #pragma unroll
    for (int j = 0; j < 4; ++j) {
      const long row = mTile + (rh << 6) + (mi << 4) + ((lane >> 4) << 2) + j;
      const float hold = bf2f(hin[row * 256 + d]);
      const float r  = sigm(acc[mi][0][j] + bir + acc[mi][3][j] + bhr);
      const float z  = sigm(acc[mi][1][j] + biz + acc[mi][4][j] + bhz);
      const float n  = tanhf(acc[mi][2][j] + bin_ + r * (acc[mi][5][j] + bhn));
      hout[row * 256 + d] = f2bf((1.f - z) * n + z * hold);
    }
  }
}

// ---------------------------------------------------------------------------
// Mega-prep: one launch for emb->bf16, embedding gather, all weight cvt,
// gw straight copy, b1+b2. Block ranges:
//   [0, V8) emb cvt | [V8, V8+Nn8) gather | tail: weights/b12/gw
// ---------------------------------------------------------------------------
__global__ void k_pre(const int* __restrict__ x, const float* __restrict__ emb,
                      unsigned short* __restrict__ embb, unsigned short* __restrict__ h,
                      const float* __restrict__ wih, const float* __restrict__ whh,
                      const float* __restrict__ W1, const float* __restrict__ W2,
                      const float* __restrict__ W3, const float* __restrict__ b1,
                      const float* __restrict__ b2, const float* __restrict__ gw,
                      unsigned short* __restrict__ wihb, unsigned short* __restrict__ whhb,
                      unsigned short* __restrict__ w1b, unsigned short* __restrict__ w2b,
                      unsigned short* __restrict__ w3b, float* __restrict__ b12,
                      unsigned short* __restrict__ gwb, int V8, int Nn8)
{
  const int b = blockIdx.x, t = threadIdx.x;
  if (b < V8) {
    const long i = (long)b * 256 + t;           // one per 8 elems of emb
    const f32x4 a = *(const f32x4*)(emb + i * 8);
    const f32x4 c = *(const f32x4*)(emb + i * 8 + 4);
    *(uint4*)(embb + i * 8) = pack8(a, c);
  } else if (b < V8 + Nn8) {
    const long i = (long)(b - V8) * 256 + t;    // one per 8 dims of h
    const long node = i >> 5;
    const int  d0 = ((int)i & 31) << 3;
    const long row = (long)x[node] - 1;         // 1-based ids
    const float* p = emb + row * 256 + d0;
    const f32x4 a = *(const f32x4*)p;
    const f32x4 c = *(const f32x4*)(p + 4);
    *(uint4*)(h + node * 256 + d0) = pack8(a, c);
  } else {
    const int bw = b - V8 - Nn8;
    const float* src; unsigned short* dst; long base;
    if (bw < 96)       { src = wih; dst = wihb; base = bw; }
    else if (bw < 192) { src = whh; dst = whhb; base = bw - 96; }
    else if (bw < 224) { src = W1;  dst = w1b;  base = bw - 192; }
    else if (bw < 256) { src = W2;  dst = w2b;  base = bw - 224; }
    else if (bw < 320) { src = W3;  dst = w3b;  base = bw - 256; }
    else if (bw == 320) { b12[t] = b1[t] + b2[t]; return; }
    else               { src = gw;  dst = gwb;  base = bw - 321; }
    const long i = base * 256 + t;
    const f32x4 a = *(const f32x4*)(src + i * 8);
    const f32x4 c = *(const f32x4*)(src + i * 8 + 4);
    *(uint4*)(dst + i * 8) = pack8(a, c);
  }
}

// per-graph scatter-add: block g handles its 20 nodes / 40 edges; thread owns dim d
__global__ void k_scatter(const unsigned short* __restrict__ m, const int* __restrict__ ei,
                          unsigned short* __restrict__ agg, int E)
{
  __shared__ float aggs[20 * 256];
  __shared__ int es[40], ed[40];
  const int g = blockIdx.x;
  const int d = threadIdx.x;
  if (d < 40) es[d] = ei[g * 40 + d];
  if (d >= 128 && d < 168) ed[d - 128] = ei[E + g * 40 + (d - 128)];
  #pragma unroll
  for (int i = 0; i < 20; ++i) aggs[i * 256 + d] = 0.f;
  __syncthreads();
  for (int e = 0; e < 40; ++e) {
    const float mv = bf2f(m[(long)es[e] * 256 + d]);
    const int loc = ed[e] - g * 20;
    aggs[loc * 256 + d] += mv;     // thread-private column: no races
  }
  const long base = (long)g * (20 * 256);
  #pragma unroll
  for (int i = 0; i < 20; ++i)
    agg[base + i * 256 + d] = f2bf(aggs[i * 256 + d]);
}

// v_n gather + cat[ :256] write; last-node index via inline binsearch on batch
__global__ void k_vn(const unsigned short* __restrict__ h, const int* __restrict__ batch,
                     unsigned short* __restrict__ vn, unsigned short* __restrict__ cat, int n)
{
  const long i = (long)blockIdx.x * 256 + threadIdx.x;
  const long g = i >> 5;
  const int  d0 = ((int)i & 31) << 3;
  int lo = 0, hi = n;                     // first idx with batch[idx] > g
  while (lo < hi) { const int mid = (lo + hi) >> 1; if (batch[mid] > (int)g) hi = mid; else lo = mid + 1; }
  const uint4 v = *(const uint4*)(h + (long)(lo - 1) * 256 + d0);
  *(uint4*)(vn + g * 256 + d0) = v;
  *(uint4*)(cat + g * 512 + d0) = v;
}

__global__ void k_sg(const float* __restrict__ alph2, const float* __restrict__ qb,
                     const unsigned short* __restrict__ h, unsigned short* __restrict__ cat, int Nn)
{
  __shared__ float al[20];
  const int g = blockIdx.x, d = threadIdx.x;
  if (d < 20) {
    const int n = g * 20 + d;
    al[d] = qb[0] + alph2[n] + alph2[Nn + n] + alph2[2 * Nn + n] + alph2[3 * Nn + n];
  }
  __syncthreads();
  float s = 0.f;
  const unsigned short* hp = h + (long)g * 20 * 256 + d;
  #pragma unroll
  for (int i = 0; i < 20; ++i) s += al[i] * bf2f(hp[i * 256]);
  cat[(long)g * 512 + 256 + d] = f2bf(s);
}

// ---------------------------------------------------------------------------
extern "C" void kernel_launch(void* const* d_in, const int* in_sizes, int n_in,
                              void* d_out, int out_size, void* d_ws, size_t ws_size,
                              hipStream_t stream)
{
  const int*   x     = (const int*)  d_in[0];
  const int*   ei    = (const int*)  d_in[1];
  const int*   batch = (const int*)  d_in[2];
  const float* emb   = (const float*)d_in[3];
  const float* gw    = (const float*)d_in[4];
  const float* wih   = (const float*)d_in[5];
  const float* whh   = (const float*)d_in[6];
  const float* bih   = (const float*)d_in[7];
  const float* bhh   = (const float*)d_in[8];
  const float* W1    = (const float*)d_in[9];
  const float* b1    = (const float*)d_in[10];
  const float* W2    = (const float*)d_in[11];
  const float* b2    = (const float*)d_in[12];
  const float* qw    = (const float*)d_in[13];
  const float* qb    = (const float*)d_in[14];
  const float* W3    = (const float*)d_in[15];
  const float* b3    = (const float*)d_in[16];

  const int Nn = in_sizes[0];           // 81920 nodes
  const int E  = in_sizes[1] / 2;       // 163840 edges
  const int V  = in_sizes[3] / 256;     // 50000 vocab
  const int B  = out_size / V;          // 4096 graphs

  char* w = (char*)d_ws;
  auto take = [&](size_t bytes) { char* r = w; w += (bytes + 1023) & ~(size_t)1023; return r; };
  unsigned short* h_   = (unsigned short*)take((size_t)Nn * 256 * 2);
  unsigned short* m_   = (unsigned short*)take((size_t)Nn * 256 * 2);
  unsigned short* agg_ = (unsigned short*)take((size_t)Nn * 256 * 2);
  unsigned short* embb = (unsigned short*)take((size_t)V * 256 * 2);
  unsigned short* gwb  = (unsigned short*)take((size_t)2 * 65536 * 2);
  unsigned short* wihb = (unsigned short*)take((size_t)768 * 256 * 2);
  unsigned short* whhb = (unsigned short*)take((size_t)768 * 256 * 2);
  unsigned short* wp0  = (unsigned short*)take((size_t)768 * 256 * 2);
  unsigned short* wp1  = (unsigned short*)take((size_t)768 * 256 * 2);
  unsigned short* w1b  = (unsigned short*)take((size_t)65536 * 2);
  unsigned short* w2b  = (unsigned short*)take((size_t)65536 * 2);
  unsigned short* w3b  = (unsigned short*)take((size_t)131072 * 2);
  unsigned short* vnb  = (unsigned short*)take((size_t)B * 256 * 2);
  unsigned short* catb = (unsigned short*)take((size_t)B * 512 * 2);
  unsigned short* shb  = (unsigned short*)take((size_t)B * 256 * 2);
  float*          b12  = (float*)take(256 * 4);
  float*          alph2= (float*)take((size_t)4 * Nn * 4);
  float*          vw1  = (float*)take((size_t)B * 256 * 4);

  const int MBn = Nn / 128;             // 640
  const int MBb = B / 128;              // 32
  const int V8  = V / 8;                // 6250
  const int Nn8 = Nn / 8;               // 10240
  const int MB2 = B / 256;              // 16
  const int NB2 = (V + 255) / 256;      // 196

  // --- prep (single launch): emb cvt + gather + weight cvt ---
  k_pre<<<dim3(V8 + Nn8 + 385), 256, 0, stream>>>(x, emb, embb, h_,
      wih, whh, W1, W2, W3, b1, b2, gw, wihb, whhb, w1b, w2b, w3b, b12, gwb, V8, Nn8);

  // --- fused layer weights: Wp[i] = wih @ gw[i]^T  (768x256, tiny) ---
  gemm_bt<1, false><<<dim3(2, 6), 256, 0, stream>>>(wihb, gwb, nullptr, wp0,
                                                    nullptr, nullptr, nullptr, 768, 256, 256);
  gemm_bt<1, false><<<dim3(2, 6), 256, 0, stream>>>(wihb, gwb + 65536, nullptr, wp1,
                                                    nullptr, nullptr, nullptr, 768, 256, 256);

  // --- 2x GatedGraphConv + fused GRUCell (h ping-pongs h_ <-> m_) ---
  // m-GEMM eliminated: gi = scatter(h) @ Wp^T  (associativity of linear ops)
  unsigned short* hc = h_;
  unsigned short* mb = m_;
  for (int L = 0; L < 2; ++L) {
    k_scatter<<<dim3(B), 256, 0, stream>>>(hc, ei, agg_, E);
    k_ggru<<<dim3(4, MBn), 512, 81920, stream>>>(agg_, hc, (L == 0 ? wp0 : wp1), whhb,
                                                 bih, bhh, mb);
    unsigned short* t = hc; hc = mb; mb = t;    // h' now lives in old m buffer
  }
  // after 2 swaps hc == h_ again

  // --- attention readout ---
  k_vn<<<dim3(B * 32 / 256), 256, 0, stream>>>(hc, batch, vnb, catb, Nn);
  gemm_bt<0, true><<<dim3(2, MBb), 256, 0, stream>>>(vnb, w1b, b12, vw1,
                                                     nullptr, nullptr, nullptr, B, 256, 256);
  // fused: alph2 slices = partial sigmoid(vw1[batch]+h@W2^T) . qw
  gemm_bt<2, false><<<dim3(2, MBn), 256, 0, stream>>>(hc, w2b, nullptr, alph2,
                                                      vw1, qw, batch, Nn, 256, 256);
  k_sg<<<dim3(B), 256, 0, stream>>>(alph2, qb, hc, catb, Nn);
  gemm_bt<1, true><<<dim3(2, MBb), 256, 0, stream>>>(catb, w3b, b3, shb,
                                                     nullptr, nullptr, nullptr, B, 256, 512);

  // --- scores = s_h @ emb^T -> d_out (f32); 256^2-tile stage-traffic-halved ---
  gemm256<<<dim3(NB2, MB2), 512, 131072, stream>>>(shb, embb, (float*)d_out, B, V, 256);

  (void)n_in; (void)ws_size;
}